// Round 11
// baseline (422.928 us; speedup 1.0000x reference)
//
#include <hip/hip_runtime.h>

#define DEV __device__ __forceinline__

typedef __attribute__((ext_vector_type(8))) short bfx8;
typedef __attribute__((ext_vector_type(4))) float fx4;

typedef __attribute__((address_space(3))) unsigned int as3_u32;
typedef const __attribute__((address_space(1))) unsigned int as1_u32c;

DEV void gl_lds16(const void* g, const void* l) {
  __builtin_amdgcn_global_load_lds((as1_u32c*)(unsigned long long)g,
                                   (as3_u32*)(unsigned long long)l, 16, 0, 0);
}

DEV short f2bf(float f) {
  unsigned u = __float_as_uint(f);
  u += 0x7fffu + ((u >> 16) & 1u);
  return (short)(u >> 16);
}
DEV float bf2f(short s) {
  return __uint_as_float(((unsigned)(unsigned short)s) << 16);
}
DEV float gelu_f(float x) { return 0.5f * x * (1.0f + erff(x * 0.70710678118654752f)); }

#define MFMA16(acc, a, b) (acc) = __builtin_amdgcn_mfma_f32_16x16x32_bf16((a), (b), (acc), 0, 0, 0)

// ---------------- prep: all weight conversions + text path + small precomputes (one dispatch) ----------------
struct PrepArgs {
  const float *w1, *inw, *ow, *tw, *e1w, *e2w, *txt, *w2, *e1b, *ob, *tb, *inb;
  short *W1bf, *Wqkv, *Wo, *Wtxt, *Wep1, *Wep2, *W2t, *Wcomb;
  float *ebc, *khv, *vhv;
};

__global__ __launch_bounds__(256) void prep(PrepArgs a) {
  __shared__ char shmem[34816];
  const int bid = (int)blockIdx.x;
  const int t = threadIdx.x;
  if (bid < 290) {
    // f32 -> bf16 weight conversions
    const float* src; short* dst; int st;
    if (bid < 32)       { src = a.w1;  dst = a.W1bf; st = 0; }
    else if (bid < 128) { src = a.inw; dst = a.Wqkv; st = 32; }
    else if (bid < 160) { src = a.ow;  dst = a.Wo;   st = 128; }
    else if (bid < 224) { src = a.tw;  dst = a.Wtxt; st = 160; }
    else if (bid < 288) { src = a.e1w; dst = a.Wep1; st = 224; }
    else                { src = a.e2w; dst = a.Wep2; st = 288; }
    long i = ((long)(bid - st) * 256 + t) * 8;
    bfx8 o;
    #pragma unroll
    for (int j = 0; j < 8; ++j) o[j] = f2bf(src[i + j]);
    *(bfx8*)(dst + i) = o;
  } else if (bid < 1058) {
    // conv2_w (768,256,3,3) -> W2t [tap][o][c]
    int oc = (bid - 290) * 256 + t;
    const float* s = a.w2 + (long)oc * 9;
    float v[9];
    #pragma unroll
    for (int j = 0; j < 9; ++j) v[j] = s[j];
    #pragma unroll
    for (int tap = 0; tap < 9; ++tap)
      a.W2t[(long)tap * (768 * 256) + oc] = f2bf(v[tap]);
  } else if (bid < 1122) {
    // ebc[n] = e1b[n] + sum_c ob[c]*e1w[n][c]; 4 rows/block
    int n = (bid - 1058) * 4 + (t >> 6);
    int lane = t & 63;
    float s = 0.0f;
    #pragma unroll
    for (int i = 0; i < 4; ++i) {
      int c = lane + 64 * i;
      s += a.ob[c] * a.e1w[(long)n * 512 + c];
    }
    #pragma unroll
    for (int off = 1; off < 64; off <<= 1) s += __shfl_xor(s, off);
    if (lane == 0) a.ebc[n] = a.e1b[n] + s;
  } else if (bid < 1130) {
    // text path (f32 sources): tmean -> tfb -> khv/vhv per batch
    float* tmean = (float*)shmem;            // [4][512]
    float* tfb = (float*)(shmem + 8192);     // [4][256]
    const int b = bid - 1122;
    {
      int key = t >> 6, d0 = (t & 63) * 8;
      float s[8] = {};
      const float* src = a.txt + ((long)(b * 64 + key * 16)) * 512 + d0;
      for (int i = 0; i < 16; ++i) {
        fx4 v0 = *(const fx4*)(src + (long)i * 512);
        fx4 v1 = *(const fx4*)(src + (long)i * 512 + 4);
        #pragma unroll
        for (int j = 0; j < 4; ++j) { s[j] += v0[j]; s[4 + j] += v1[j]; }
      }
      #pragma unroll
      for (int j = 0; j < 8; ++j) tmean[key * 512 + d0 + j] = s[j] * (1.0f / 16.0f);
    }
    __syncthreads();
    {
      int n = t;
      float a0 = 0, a1 = 0, a2 = 0, a3 = 0;
      const float* wr = a.tw + (long)n * 512;
      for (int d = 0; d < 512; d += 4) {
        fx4 w = *(const fx4*)(wr + d);
        #pragma unroll
        for (int j = 0; j < 4; ++j) {
          float wf = w[j];
          a0 += tmean[0 * 512 + d + j] * wf;
          a1 += tmean[1 * 512 + d + j] * wf;
          a2 += tmean[2 * 512 + d + j] * wf;
          a3 += tmean[3 * 512 + d + j] * wf;
        }
      }
      float bias = a.tb[n];
      tfb[0 * 256 + n] = a0 + bias; tfb[1 * 256 + n] = a1 + bias;
      tfb[2 * 256 + n] = a2 + bias; tfb[3 * 256 + n] = a3 + bias;
    }
    __syncthreads();
    {
      int n = t;
      const float* wk = a.inw + (long)(256 + n) * 256;
      const float* wvp = a.inw + (long)(512 + n) * 256;
      float k0=0,k1=0,k2=0,k3=0,v0=0,v1=0,v2=0,v3=0;
      for (int d = 0; d < 256; d += 4) {
        fx4 wkv = *(const fx4*)(wk + d);
        fx4 wvv = *(const fx4*)(wvp + d);
        #pragma unroll
        for (int j = 0; j < 4; ++j) {
          float f0 = tfb[0*256+d+j], f1 = tfb[1*256+d+j], f2 = tfb[2*256+d+j], f3 = tfb[3*256+d+j];
          float kw = wkv[j], vw = wvv[j];
          k0 += f0*kw; k1 += f1*kw; k2 += f2*kw; k3 += f3*kw;
          v0 += f0*vw; v1 += f1*vw; v2 += f2*vw; v3 += f3*vw;
        }
      }
      float bk = a.inb[256+n], bv = a.inb[512+n];
      a.khv[(b*4+0)*256+n]=k0+bk; a.khv[(b*4+1)*256+n]=k1+bk;
      a.khv[(b*4+2)*256+n]=k2+bk; a.khv[(b*4+3)*256+n]=k3+bk;
      a.vhv[(b*4+0)*256+n]=v0+bv; a.vhv[(b*4+1)*256+n]=v1+bv;
      a.vhv[(b*4+2)*256+n]=v2+bv; a.vhv[(b*4+3)*256+n]=v3+bv;
    }
  } else {
    // Wcomb[m][d] = sum_c E1a[m][c] * ow[c][d]  (A from e1w f32, B = in-LDS transpose of ow)
    short* Bt = (short*)shmem;  // [64][264]
    const int idx = bid - 1130;
    const int bx = idx & 3, by = idx >> 2;
    const int lane = t & 63, w = t >> 6;
    const int lg = lane >> 4, li = lane & 15;
    const int m0 = by * 64, n0 = bx * 64;
    for (int id2 = t; id2 < 64 * 256; id2 += 256) {
      int c = id2 >> 6, d = id2 & 63;
      Bt[d * 264 + c] = f2bf(a.ow[(long)c * 256 + n0 + d]);
    }
    __syncthreads();
    fx4 acc[4] = {};
    const float* aR = a.e1w + (long)(m0 + w * 16 + li) * 512 + lg * 8;
    for (int kc = 0; kc < 256; kc += 32) {
      fx4 lo = *(const fx4*)(aR + kc);
      fx4 hi = *(const fx4*)(aR + kc + 4);
      bfx8 av;
      av[0] = f2bf(lo[0]); av[1] = f2bf(lo[1]); av[2] = f2bf(lo[2]); av[3] = f2bf(lo[3]);
      av[4] = f2bf(hi[0]); av[5] = f2bf(hi[1]); av[6] = f2bf(hi[2]); av[7] = f2bf(hi[3]);
      #pragma unroll
      for (int ni = 0; ni < 4; ++ni) {
        bfx8 bv = *(const bfx8*)(&Bt[(ni * 16 + li) * 264 + kc + lg * 8]);
        MFMA16(acc[ni], av, bv);
      }
    }
    #pragma unroll
    for (int ni = 0; ni < 4; ++ni)
      #pragma unroll
      for (int r = 0; r < 4; ++r)
        a.Wcomb[(long)(m0 + w * 16 + 4 * lg + r) * 256 + n0 + ni * 16 + li] = f2bf(acc[ni][r]);
  }
}

// ---------------- fused transpose + conv1(1x1) + gelu (+ zero borders of xP) ----------------
DEV int axc(int p, int c) { return p * 260 + (c ^ (((p >> 2) & 7) << 2)); }

__global__ __launch_bounds__(256) void tc1(const float* fm, const short* W1bf,
                                           const float* b1, short* xP) {
  __shared__ float Af[64 * 260];
  const int lane = threadIdx.x & 63, wv = threadIdx.x >> 6;
  const int lg = lane >> 4, li = lane & 15;
  const int y = blockIdx.x & 63, b = blockIdx.x >> 6;
  const int t = threadIdx.x;
  short* dstP = xP + ((long)b * 66 * 66 + (long)(y + 1) * 66 + 1) * 256;
  const bfx8 z8 = {0, 0, 0, 0, 0, 0, 0, 0};

  if (t < 64) {
    if (t < 32) *(bfx8*)(dstP - 256 + t * 8) = z8;
    else        *(bfx8*)(dstP + 64 * 256 + (t - 32) * 8) = z8;
  }
  if (y == 0) {
    short* top = xP + (long)b * 66 * 66 * 256;
    for (int i = t; i < 2112; i += 256) *(bfx8*)(top + i * 8) = z8;
  }
  if (y == 63) {
    short* bot = xP + ((long)b * 66 * 66 + 65 * 66) * 256;
    for (int i = t; i < 2112; i += 256) *(bfx8*)(bot + i * 8) = z8;
  }

  const float* src = fm + (long)b * 256 * 4096 + y * 64;
  #pragma unroll
  for (int i = 0; i < 16; ++i) {
    int chunk = i * 256 + t;
    int c = chunk >> 4;
    int q = chunk & 15;
    fx4 v = *(const fx4*)(src + (long)c * 4096 + q * 4);
    #pragma unroll
    for (int j = 0; j < 4; ++j) Af[axc(q * 4 + j, c)] = v[j];
  }
  __syncthreads();

  fx4 acc[4][4] = {};
  const short* Bb = W1bf + (long)(wv * 64 + li) * 256 + lg * 8;
  for (int c0 = 0; c0 < 256; c0 += 32) {
    bfx8 af[4], bfr[4];
    #pragma unroll
    for (int mi = 0; mi < 4; ++mi) {
      int p = mi * 16 + li;
      fx4 lo = *(const fx4*)(&Af[axc(p, c0 + lg * 8)]);
      fx4 hi = *(const fx4*)(&Af[axc(p, c0 + lg * 8 + 4)]);
      bfx8 tt;
      tt[0] = f2bf(lo[0]); tt[1] = f2bf(lo[1]); tt[2] = f2bf(lo[2]); tt[3] = f2bf(lo[3]);
      tt[4] = f2bf(hi[0]); tt[5] = f2bf(hi[1]); tt[6] = f2bf(hi[2]); tt[7] = f2bf(hi[3]);
      af[mi] = tt;
    }
    #pragma unroll
    for (int ni = 0; ni < 4; ++ni) bfr[ni] = *(const bfx8*)(Bb + ni * 16 * 256 + c0);
    #pragma unroll
    for (int mi = 0; mi < 4; ++mi)
      #pragma unroll
      for (int ni = 0; ni < 4; ++ni) MFMA16(acc[mi][ni], af[mi], bfr[ni]);
  }

  #pragma unroll
  for (int mi = 0; mi < 4; ++mi)
    #pragma unroll
    for (int ni = 0; ni < 4; ++ni) {
      int col = wv * 64 + ni * 16 + li;
      float bias = b1[col];
      #pragma unroll
      for (int r = 0; r < 4; ++r) {
        int x = mi * 16 + 4 * lg + r;
        dstP[(long)x * 256 + col] = f2bf(gelu_f(acc[mi][ni][r] + bias));
      }
    }
}

// ---------------- 128x128 MFMA GEMM body, BK=64 ----------------
struct GemmP {
  const short* A; const short* B; void* O;
  const float* biasN; const float* biasM;
  long lda, ldb, ldo, sA, sB, sO;
  int M, N, K, outF32, act;
  int aShift;
  long sBN, sBM;
};

DEV void gemm_body64(const GemmP& g, int bx, int by, int bz) {
  __shared__ short As[2 * 128 * 32];
  __shared__ short Bs[2 * 128 * 32];
  const int lane = threadIdx.x & 63, wv = threadIdx.x >> 6;
  const int wm = wv >> 1, wn = wv & 1;
  const int lg = lane >> 4, li = lane & 15;
  const int m0 = by * 128, n0 = bx * 128, z = bz;
  const short* A = g.A + (long)z * g.sA + (long)(n0 >> 8) * g.aShift;
  const short* B = g.B + (long)z * g.sB;
  const int srow = wv * 16 + (lane >> 2);
  const int scol = (lane & 3) * 8;
  const short* pA0 = A + (long)(m0 + srow) * g.lda + scol;
  const short* pA1 = A + (long)(m0 + 64 + srow) * g.lda + scol;
  const short* pB0 = B + (long)(n0 + srow) * g.ldb + scol;
  const short* pB1 = B + (long)(n0 + 64 + srow) * g.ldb + scol;
  short* ldsA = As + wv * 512;
  short* ldsB = Bs + wv * 512;
  const short* aRd = As + (wm * 64 + li) * 32 + lg * 8;
  const short* bRd = Bs + (wn * 64 + li) * 32 + lg * 8;

  fx4 acc[4][4] = {};
  for (int kc = 0; kc < g.K; kc += 64) {
    gl_lds16(pA0 + kc, ldsA);
    gl_lds16(pA1 + kc, ldsA + 2048);
    gl_lds16(pA0 + kc + 32, ldsA + 4096);
    gl_lds16(pA1 + kc + 32, ldsA + 6144);
    gl_lds16(pB0 + kc, ldsB);
    gl_lds16(pB1 + kc, ldsB + 2048);
    gl_lds16(pB0 + kc + 32, ldsB + 4096);
    gl_lds16(pB1 + kc + 32, ldsB + 6144);
    __syncthreads();
    #pragma unroll
    for (int kk = 0; kk < 2; ++kk) {
      bfx8 af[4], bf[4];
      #pragma unroll
      for (int mi = 0; mi < 4; ++mi) af[mi] = *(const bfx8*)(aRd + kk * 4096 + mi * 16 * 32);
      #pragma unroll
      for (int ni = 0; ni < 4; ++ni) bf[ni] = *(const bfx8*)(bRd + kk * 4096 + ni * 16 * 32);
      #pragma unroll
      for (int mi = 0; mi < 4; ++mi)
        #pragma unroll
        for (int ni = 0; ni < 4; ++ni)
          MFMA16(acc[mi][ni], af[mi], bf[ni]);
    }
    __syncthreads();
  }

  #pragma unroll
  for (int mi = 0; mi < 4; ++mi)
    #pragma unroll
    for (int ni = 0; ni < 4; ++ni) {
      int col = n0 + wn * 64 + ni * 16 + li;
      int rowb = m0 + wm * 64 + mi * 16 + 4 * lg;
      float bn = g.biasN ? g.biasN[(long)z * g.sBN + col] : 0.0f;
      #pragma unroll
      for (int r = 0; r < 4; ++r) {
        int row = rowb + r;
        float v = acc[mi][ni][r] + bn;
        if (g.biasM) v += g.biasM[(long)z * g.sBM + row];
        if (g.act == 1) v = gelu_f(v);
        long oidx = (long)z * g.sO + (long)row * g.ldo + col;
        if (g.outF32) ((float*)g.O)[oidx] = v;
        else ((short*)g.O)[oidx] = f2bf(v);
      }
    }
}

// packed qk-proj (ids 0..1023) + v-proj (ids 1024..1535), XCD-swizzled
__global__ __launch_bounds__(256) void projk(GemmP gq, GemmP gv) {
  int bid = (int)blockIdx.x;
  int id = (bid & 7) * 192 + (bid >> 3);
  if (id < 1024) {
    int z = id >> 7, r = id & 127;
    gemm_body64(gq, r & 3, r >> 2, z);
  } else {
    int j = id - 1024;
    int z = j >> 6, r = j & 63;
    gemm_body64(gv, r & 31, r >> 5, z);
  }
}

// ---------------- conv2 3x3 implicit GEMM, BK=64, incremental offsets, XCD-swizzled ----------------
__global__ __launch_bounds__(256) void conv2g(const short* xP, const short* W2t,
                                              const float* b2, short* qkv, float* stats) {
  __shared__ short As[2 * 128 * 32];
  __shared__ short Bs[2 * 128 * 32];
  __shared__ float red[4][4];
  const int lane = threadIdx.x & 63, wv = threadIdx.x >> 6;
  const int wm = wv >> 1, wn = wv & 1;
  const int lg = lane >> 4, li = lane & 15;
  const int w = ((int)blockIdx.x & 7) * 192 + ((int)blockIdx.x >> 3);
  const int n0 = (w % 6) * 128;
  const int by = w / 6;
  const int b = by >> 5, ypair = by & 31;
  const short* xPb = xP + (long)b * 66 * 66 * 256;

  const int srow = wv * 16 + (lane >> 2);
  const int scol = (lane & 3) * 8;
  long baseA[2], baseB[2];
  #pragma unroll
  for (int j = 0; j < 2; ++j) {
    int r = j * 64 + srow;
    int yy = 2 * ypair + (r >> 6);
    int x = r & 63;
    baseA[j] = ((long)yy * 66 + x) * 256 + scol;
    baseB[j] = (long)(n0 + r) * 256 + scol;
  }
  short* ldsA = As + wv * 512;
  short* ldsB = Bs + wv * 512;
  const short* aRd = As + (wm * 64 + li) * 32 + lg * 8;
  const short* bRd = Bs + (wn * 64 + li) * 32 + lg * 8;

  fx4 acc[4][4] = {};
  long aoff = 0, boff = 0;
  int txc = 0;
  for (int ks = 0; ks < 36; ++ks) {
    gl_lds16(xPb + baseA[0] + aoff, ldsA);
    gl_lds16(xPb + baseA[1] + aoff, ldsA + 2048);
    gl_lds16(xPb + baseA[0] + aoff + 32, ldsA + 4096);
    gl_lds16(xPb + baseA[1] + aoff + 32, ldsA + 6144);
    gl_lds16(W2t + baseB[0] + boff, ldsB);
    gl_lds16(W2t + baseB[1] + boff, ldsB + 2048);
    gl_lds16(W2t + baseB[0] + boff + 32, ldsB + 4096);
    gl_lds16(W2t + baseB[1] + boff + 32, ldsB + 6144);
    __syncthreads();
    #pragma unroll
    for (int kk = 0; kk < 2; ++kk) {
      bfx8 af[4], bf[4];
      #pragma unroll
      for (int mi = 0; mi < 4; ++mi) af[mi] = *(const bfx8*)(aRd + kk * 4096 + mi * 16 * 32);
      #pragma unroll
      for (int ni = 0; ni < 4; ++ni) bf[ni] = *(const bfx8*)(bRd + kk * 4096 + ni * 16 * 32);
      #pragma unroll
      for (int mi = 0; mi < 4; ++mi)
        #pragma unroll
        for (int ni = 0; ni < 4; ++ni)
          MFMA16(acc[mi][ni], af[mi], bf[ni]);
    }
    __syncthreads();
    aoff += 64; boff += 64;
    if ((ks & 3) == 3) {
      boff += 196608 - 256;           // next tap's weight plane
      if (txc == 2) { aoff += 16128; txc = 0; }  // dx wrap -> next dy row
      else ++txc;                      // dx advance (+256 already accumulated)
    }
  }

  const int g0 = n0 / 192;
  const int bnd = (g0 + 1) * 192;
  float sA = 0.0f, s2A = 0.0f, sB = 0.0f, s2B = 0.0f;
  const long prow0 = (long)b * 4096 + (long)ypair * 128 + wm * 64 + 4 * lg;
  #pragma unroll
  for (int ni = 0; ni < 4; ++ni) {
    int col = n0 + wn * 64 + ni * 16 + li;
    float bias = b2[col];
    bool inA = (col < bnd);
    #pragma unroll
    for (int mi = 0; mi < 4; ++mi) {
      long rb = prow0 + mi * 16;
      #pragma unroll
      for (int r = 0; r < 4; ++r) {
        float v = acc[mi][ni][r] + bias;
        if (inA) { sA += v; s2A += v * v; } else { sB += v; s2B += v * v; }
        qkv[(rb + r) * 768 + col] = f2bf(v);
      }
    }
  }
  #pragma unroll
  for (int off = 1; off < 64; off <<= 1) {
    sA += __shfl_xor(sA, off);  s2A += __shfl_xor(s2A, off);
    sB += __shfl_xor(sB, off);  s2B += __shfl_xor(s2B, off);
  }
  if (lane == 0) { red[wv][0] = sA; red[wv][1] = s2A; red[wv][2] = sB; red[wv][3] = s2B; }
  __syncthreads();
  if (threadIdx.x == 0) {
    float a1 = red[0][0] + red[1][0] + red[2][0] + red[3][0];
    float a2 = red[0][1] + red[1][1] + red[2][1] + red[3][1];
    atomicAdd(&stats[(b * 4 + g0) * 2], a1);
    atomicAdd(&stats[(b * 4 + g0) * 2 + 1], a2);
    if (bnd < n0 + 128) {
      float b1s = red[0][2] + red[1][2] + red[2][2] + red[3][2];
      float b2s = red[0][3] + red[1][3] + red[2][3] + red[3][3];
      atomicAdd(&stats[(b * 4 + g0 + 1) * 2], b1s);
      atomicAdd(&stats[(b * 4 + g0 + 1) * 2 + 1], b2s);
    }
  }
}

// fold GN affine into per-batch projection weights (stats finalized inline)
__global__ __launch_bounds__(256) void gn_fold(const float* stats, const float* gnw, const float* gnb,
                                               const float* inw, const float* inb,
                                               short* Wf, float* bfold) {
  const int lane = threadIdx.x & 63, wv = threadIdx.x >> 6;
  const int row = blockIdx.x * 4 + wv;
  const int b = row / 768, j = row - b * 768;
  const int cb = (j >> 8) << 8;
  const float nrm = 1.0f / (192.0f * 4096.0f);
  float part = 0.0f;
  #pragma unroll
  for (int i = 0; i < 4; ++i) {
    int c = lane + 64 * i;
    int cg = cb + c;
    int grp = cg / 192;
    float s1 = stats[(b * 4 + grp) * 2];
    float s2 = stats[(b * 4 + grp) * 2 + 1];
    float mu = s1 * nrm;
    float var = s2 * nrm - mu * mu;
    float rs = rsqrtf(var + 1e-5f);
    float s = rs * gnw[cg];
    float t = gnb[cg] - mu * s;
    float wv_ = inw[(long)j * 256 + c];
    Wf[(long)row * 256 + c] = f2bf(wv_ * s);
    part += t * wv_;
  }
  #pragma unroll
  for (int off = 1; off < 64; off <<= 1) part += __shfl_xor(part, off);
  if (lane == 0) bfold[row] = inb[j] + part;
}

// ---------------- local attention + last-block-per-batch global chain ----------------
#define GP 272

DEV void mm_stage(const short* srcA, const short* Bw, long ldb, const float* biasN,
                  short* dstL, float* dstG, int wv, int lg, int li) {
  fx4 acc[4][4] = {};
  const short* aRd = srcA + li * GP + lg * 8;
  const short* bR = Bw + (long)(wv * 64 + li) * ldb + lg * 8;
  for (int kc = 0; kc < 256; kc += 32) {
    bfx8 af[4], bf[4];
    #pragma unroll
    for (int mi = 0; mi < 4; ++mi) af[mi] = *(const bfx8*)(aRd + mi * 16 * GP + kc);
    #pragma unroll
    for (int ni = 0; ni < 4; ++ni) bf[ni] = *(const bfx8*)(bR + (long)ni * 16 * ldb + kc);
    #pragma unroll
    for (int mi = 0; mi < 4; ++mi)
      #pragma unroll
      for (int ni = 0; ni < 4; ++ni) MFMA16(acc[mi][ni], af[mi], bf[ni]);
  }
  #pragma unroll
  for (int mi = 0; mi < 4; ++mi)
    #pragma unroll
    for (int ni = 0; ni < 4; ++ni) {
      int col = wv * 64 + ni * 16 + li;
      float bn = biasN[col];
      #pragma unroll
      for (int r = 0; r < 4; ++r) {
        int row = mi * 16 + 4 * lg + r;
        float v = acc[mi][ni][r] + bn;
        if (dstL) dstL[row * GP + col] = f2bf(v);
        else dstG[(long)row * 256 + col] = v;
      }
    }
}

union ShU {
  short Pl[4 * 64 * 72];
  struct {
    short bufA[64 * GP];
    short bufB[64 * GP];
    float kh[4][256];
    float vh[4][256];
    float scb[16];
    float pb[16];
  } g;
};

__global__ __launch_bounds__(256) void attn_lg(
    const short* qk, const short* vhT, const float* khv, const float* vhv,
    const short* Wo, const short* Wqkv, const short* Wep1,
    const float* ob, const float* inb, const float* ebc,
    short* oat, short* oatm, float* gcon, int* cnt) {
  __shared__ ShU sh;
  __shared__ int elect_s;
  const int t = threadIdx.x;
  const int lane = t & 63, h = t >> 6;
  const int lg = lane >> 4, li = lane & 15;
  const int bw = blockIdx.x;
  const int b = bw >> 6, wY = bw & 63;
  const long p0 = (long)bw * 64;

  bfx8 qf[4][2], kf[4][2];
  #pragma unroll
  for (int mi = 0; mi < 4; ++mi)
    #pragma unroll
    for (int ks = 0; ks < 2; ++ks) {
      qf[mi][ks] = *(const bfx8*)(qk + (p0 + 16 * mi + li) * 512 + h * 64 + 32 * ks + 8 * lg);
      kf[mi][ks] = *(const bfx8*)(qk + (p0 + 16 * mi + li) * 512 + 256 + h * 64 + 32 * ks + 8 * lg);
    }
  fx4 s[4][4] = {};
  #pragma unroll
  for (int mi = 0; mi < 4; ++mi)
    #pragma unroll
    for (int ni = 0; ni < 4; ++ni) {
      MFMA16(s[mi][ni], qf[mi][0], kf[ni][0]);
      MFMA16(s[mi][ni], qf[mi][1], kf[ni][1]);
    }
  #pragma unroll
  for (int mi = 0; mi < 4; ++mi)
    #pragma unroll
    for (int ni = 0; ni < 4; ++ni) s[mi][ni] *= 0.125f;

  #pragma unroll
  for (int mi = 0; mi < 4; ++mi)
    #pragma unroll
    for (int r = 0; r < 4; ++r) {
      float mx = fmaxf(fmaxf(s[mi][0][r], s[mi][1][r]), fmaxf(s[mi][2][r], s[mi][3][r]));
      for (int off = 1; off < 16; off <<= 1) mx = fmaxf(mx, __shfl_xor(mx, off));
      float e[4];
      float sum = 0.0f;
      #pragma unroll
      for (int ni = 0; ni < 4; ++ni) { e[ni] = expf(s[mi][ni][r] - mx); sum += e[ni]; }
      for (int off = 1; off < 16; off <<= 1) sum += __shfl_xor(sum, off);
      float inv = 1.0f / sum;
      int row = h * 64 + 16 * mi + 4 * lg + r;
      #pragma unroll
      for (int ni = 0; ni < 4; ++ni) sh.Pl[row * 72 + 16 * ni + li] = f2bf(e[ni] * inv);
    }
  __syncthreads();

  fx4 o[4][4] = {};
  #pragma unroll
  for (int ks = 0; ks < 2; ++ks) {
    bfx8 pf[4], vf[4];
    #pragma unroll
    for (int mi = 0; mi < 4; ++mi)
      pf[mi] = *(const bfx8*)(&sh.Pl[(h * 64 + 16 * mi + li) * 72 + 32 * ks + 8 * lg]);
    #pragma unroll
    for (int ni = 0; ni < 4; ++ni)
      vf[ni] = *(const bfx8*)(vhT + ((long)(b * 256 + h * 64 + 16 * ni + li)) * 4096 + wY * 64 + 32 * ks + 8 * lg);
    #pragma unroll
    for (int mi = 0; mi < 4; ++mi)
      #pragma unroll
      for (int ni = 0; ni < 4; ++ni) MFMA16(o[mi][ni], pf[mi], vf[ni]);
  }
  #pragma unroll
  for (int mi = 0; mi < 4; ++mi)
    #pragma unroll
    for (int ni = 0; ni < 4; ++ni)
      #pragma unroll
      for (int r = 0; r < 4; ++r)
        oat[(p0 + 16 * mi + 4 * lg + r) * 256 + h * 64 + 16 * ni + li] = f2bf(o[mi][ni][r]);

  #pragma unroll
  for (int ni = 0; ni < 4; ++ni) {
    float s2 = 0.0f;
    #pragma unroll
    for (int mi = 0; mi < 4; ++mi)
      #pragma unroll
      for (int r = 0; r < 4; ++r) s2 += o[mi][ni][r];
    s2 += __shfl_xor(s2, 16);
    s2 += __shfl_xor(s2, 32);
    if (lg == 0)
      oatm[(long)bw * 256 + h * 64 + 16 * ni + li] = f2bf(s2 * (1.0f / 64.0f));
  }

  // ---- last block of batch b runs the global chain ----
  __threadfence();
  __syncthreads();   // all oatm writes issued + Pl reads done (union reuse safe)
  if (t == 0) elect_s = (atomicAdd(&cnt[b], 1) == 63) ? 1 : 0;
  __syncthreads();
  if (!elect_s) return;
  __threadfence();

  const int wv = h;
  { // stage oatm[b] -> bufA; khv/vhv -> LDS
    #pragma unroll
    for (int i = 0; i < 8; ++i) {
      int chunk = i * 256 + t;
      int row = chunk >> 5, colc = (chunk & 31) * 8;
      *(bfx8*)(sh.g.bufA + row * GP + colc) =
          *(const bfx8*)(oatm + ((long)(b * 64 + row)) * 256 + colc);
    }
    #pragma unroll
    for (int key = 0; key < 4; ++key) {
      sh.g.kh[key][t] = khv[(long)(b * 4 + key) * 256 + t];
      sh.g.vh[key][t] = vhv[(long)(b * 4 + key) * 256 + t];
    }
  }
  __syncthreads();
  mm_stage(sh.g.bufA, Wo, 256, ob, sh.g.bufB, nullptr, wv, lg, li);
  __syncthreads();
  mm_stage(sh.g.bufB, Wqkv, 256, inb, sh.g.bufA, nullptr, wv, lg, li);
  __syncthreads();
  { // 4-key attention per (window p, head hh)
    int p = t >> 2, hh = t & 3;
    const short* qr = sh.g.bufA + p * GP + hh * 64;
    float sc[4];
    #pragma unroll
    for (int key = 0; key < 4; ++key) {
      float sum = 0.0f;
      for (int d = 0; d < 64; d += 8) {
        bfx8 q8 = *(const bfx8*)(qr + d);
        #pragma unroll
        for (int j = 0; j < 8; ++j) sum += bf2f(q8[j]) * sh.g.kh[key][hh * 64 + d + j];
      }
      sc[key] = sum * 0.125f;
    }
    float mx = fmaxf(fmaxf(sc[0], sc[1]), fmaxf(sc[2], sc[3]));
    float e0 = expf(sc[0]-mx), e1 = expf(sc[1]-mx), e2 = expf(sc[2]-mx), e3 = expf(sc[3]-mx);
    float inv = 1.0f / (e0 + e1 + e2 + e3);
    e0 *= inv; e1 *= inv; e2 *= inv; e3 *= inv;
    short* orow = sh.g.bufB + p * GP + hh * 64;
    for (int d = 0; d < 64; ++d) {
      float ov = e0*sh.g.vh[0][hh*64+d] + e1*sh.g.vh[1][hh*64+d] +
                 e2*sh.g.vh[2][hh*64+d] + e3*sh.g.vh[3][hh*64+d];
      orow[d] = f2bf(ov);
    }
  }
  __syncthreads();
  mm_stage(sh.g.bufB, Wo, 256, ob, sh.g.bufA, nullptr, wv, lg, li);
  __syncthreads();
  mm_stage(sh.g.bufA, Wep1 + 256, 512, ebc, nullptr, gcon + (long)b * 64 * 256, wv, lg, li);
}

// ---------------- fused ep1 + ep2 + sigmoid: oat -> out (BK=64 staging) ----------------
__global__ __launch_bounds__(256) void ep12(const short* oat, const short* Wcomb,
                                            const short* Wep2, const float* gcon,
                                            const float* e2b, float* out) {
  __shared__ short As[2 * 128 * 32];
  __shared__ short Bs[2 * 128 * 32];
  __shared__ short hl[128 * 140];
  const int lane = threadIdx.x & 63, wv = threadIdx.x >> 6;
  const int wm = wv >> 1, wn = wv & 1;
  const int lg = lane >> 4, li = lane & 15;
  const int m0 = (int)blockIdx.x * 128;
  const int srow = wv * 16 + (lane >> 2);
  const int scol = (lane & 3) * 8;
  const short* pA0 = oat + (long)(m0 + srow) * 256 + scol;
  const short* pA1 = oat + (long)(m0 + 64 + srow) * 256 + scol;
  short* ldsA = As + wv * 512;
  short* ldsB = Bs + wv * 512;
  const short* aRd = As + (wm * 64 + li) * 32 + lg * 8;
  const short* bRd = Bs + (wn * 64 + li) * 32 + lg * 8;

  fx4 eacc[2] = {};
  for (int half = 0; half < 2; ++half) {
    const short* B = Wcomb + (long)(half * 128) * 256;
    const short* pB0 = B + (long)srow * 256 + scol;
    const short* pB1 = B + (long)(64 + srow) * 256 + scol;
    fx4 acc[4][4] = {};
    for (int kc = 0; kc < 256; kc += 64) {
      gl_lds16(pA0 + kc, ldsA);
      gl_lds16(pA1 + kc, ldsA + 2048);
      gl_lds16(pA0 + kc + 32, ldsA + 4096);
      gl_lds16(pA1 + kc + 32, ldsA + 6144);
      gl_lds16(pB0 + kc, ldsB);
      gl_lds16(pB1 + kc, ldsB + 2048);
      gl_lds16(pB0 + kc + 32, ldsB + 4096);
      gl_lds16(pB1 + kc + 32, ldsB + 6144);
      __syncthreads();
      #pragma unroll
      for (int kk = 0; kk < 2; ++kk) {
        bfx8 af[4], bf[4];
        #pragma unroll
        for (int mi = 0; mi < 4; ++mi) af[mi] = *(const bfx8*)(aRd + kk * 4096 + mi * 16 * 32);
        #pragma unroll
        for (int ni = 0; ni < 4; ++ni) bf[ni] = *(const bfx8*)(bRd + kk * 4096 + ni * 16 * 32);
        #pragma unroll
        for (int mi = 0; mi < 4; ++mi)
          #pragma unroll
          for (int ni = 0; ni < 4; ++ni)
            MFMA16(acc[mi][ni], af[mi], bf[ni]);
      }
      __syncthreads();
    }
    #pragma unroll
    for (int mi = 0; mi < 4; ++mi)
      #pragma unroll
      for (int ni = 0; ni < 4; ++ni) {
        int coll = wn * 64 + ni * 16 + li;
        int colg = half * 128 + coll;
        #pragma unroll
        for (int r = 0; r < 4; ++r) {
          int rowl = wm * 64 + mi * 16 + 4 * lg + r;
          float v = acc[mi][ni][r] + gcon[(long)((m0 + rowl) >> 6) * 256 + colg];
          hl[rowl * 140 + coll] = f2bf(gelu_f(v));
        }
      }
    __syncthreads();
    #pragma unroll
    for (int kc = 0; kc < 128; kc += 32) {
      bfx8 bf2v = *(const bfx8*)(Wep2 + (long)li * 256 + half * 128 + kc + lg * 8);
      #pragma unroll
      for (int mi = 0; mi < 2; ++mi) {
        bfx8 af = *(const bfx8*)(hl + (wv * 32 + mi * 16 + li) * 140 + kc + lg * 8);
        MFMA16(eacc[mi], af, bf2v);
      }
    }
    __syncthreads();
  }
  #pragma unroll
  for (int mi = 0; mi < 2; ++mi)
    #pragma unroll
    for (int r = 0; r < 4; ++r) {
      int row = m0 + wv * 32 + mi * 16 + 4 * lg + r;
      out[(long)row * 16 + li] = 1.0f / (1.0f + expf(-(eacc[mi][r] + e2b[li])));
    }
}

// ---------------- host ----------------
extern "C" void kernel_launch(void* const* d_in, const int* in_sizes, int n_in,
                              void* d_out, int out_size, void* d_ws, size_t ws_size,
                              hipStream_t stream) {
  (void)in_sizes; (void)n_in; (void)out_size; (void)ws_size;
  const float* fm  = (const float*)d_in[0];
  const float* txt = (const float*)d_in[1];
  const float* w1  = (const float*)d_in[2];
  const float* b1  = (const float*)d_in[3];
  const float* w2  = (const float*)d_in[4];
  const float* b2  = (const float*)d_in[5];
  const float* gnw = (const float*)d_in[6];
  const float* gnb = (const float*)d_in[7];
  const float* inw = (const float*)d_in[8];
  const float* inb = (const float*)d_in[9];
  const float* ow  = (const float*)d_in[10];
  const float* ob  = (const float*)d_in[11];
  const float* tw  = (const float*)d_in[12];
  const float* tb  = (const float*)d_in[13];
  const float* e1w = (const float*)d_in[14];
  const float* e1b = (const float*)d_in[15];
  const float* e2w = (const float*)d_in[16];
  const float* e2b = (const float*)d_in[17];
  float* out = (float*)d_out;

  char* base = (char*)d_ws;
  size_t off = 0;
  auto alloc = [&](size_t bytes) -> char* {
    char* r = base + off;
    off = (off + bytes + 255) & ~(size_t)255;
    return r;
  };
  short* W1bf = (short*)alloc(256 * 256 * 2);
  short* W2t  = (short*)alloc((size_t)9 * 768 * 256 * 2);
  short* Wqkv = (short*)alloc(768 * 256 * 2);
  short* Wo   = (short*)alloc(256 * 256 * 2);
  short* Wcomb= (short*)alloc(256 * 256 * 2);
  float* ebc  = (float*)alloc(256 * 4);
  short* Wtxt = (short*)alloc(256 * 512 * 2);
  short* Wep1 = (short*)alloc(256 * 512 * 2);
  short* Wep2 = (short*)alloc(16 * 256 * 2);
  short* xP   = (short*)alloc((size_t)8 * 66 * 66 * 256 * 2);
  short* qkv  = (short*)alloc((size_t)8 * 4096 * 768 * 2);
  float* zeros= (float*)alloc(96 * 4);     // stats[64] + cnt[8] (+pad), one memset
  float* stats= zeros;
  int*   cnt  = (int*)(zeros + 64);
  short* Wf   = (short*)alloc((size_t)8 * 768 * 256 * 2);
  float* bfold= (float*)alloc((size_t)8 * 768 * 4);
  short* qk   = (short*)alloc((size_t)32768 * 512 * 2);
  short* vhT  = (short*)alloc((size_t)8 * 4096 * 256 * 2);
  short* oat  = (short*)alloc((size_t)8 * 4096 * 256 * 2);
  short* oatm = (short*)alloc(512 * 256 * 2);
  float* khv  = (float*)alloc(8 * 4 * 256 * 4);
  float* vhv  = (float*)alloc(8 * 4 * 256 * 4);
  float* gcon = (float*)alloc(512 * 256 * 4);

  hipMemsetAsync(zeros, 0, 96 * 4, stream);

  PrepArgs pa;
  pa.w1 = w1; pa.inw = inw; pa.ow = ow; pa.tw = tw; pa.e1w = e1w; pa.e2w = e2w;
  pa.txt = txt; pa.w2 = w2; pa.e1b = e1b; pa.ob = ob; pa.tb = tb; pa.inb = inb;
  pa.W1bf = W1bf; pa.Wqkv = Wqkv; pa.Wo = Wo; pa.Wtxt = Wtxt; pa.Wep1 = Wep1;
  pa.Wep2 = Wep2; pa.W2t = W2t; pa.Wcomb = Wcomb;
  pa.ebc = ebc; pa.khv = khv; pa.vhv = vhv;
  prep<<<1146, 256, 0, stream>>>(pa);

  tc1<<<512, 256, 0, stream>>>(fm, W1bf, b1, xP);

  conv2g<<<1536, 256, 0, stream>>>(xP, W2t, b2, qkv, stats);

  gn_fold<<<1536, 256, 0, stream>>>(stats, gnw, gnb, inw, inb, Wf, bfold);

  { // packed qk + v projections
    GemmP gq{};
    gq.A = qkv; gq.lda = 768; gq.sA = 4096L * 768;
    gq.B = Wf; gq.ldb = 256; gq.sB = 768L * 256;
    gq.O = qk; gq.ldo = 512; gq.sO = 4096L * 512;
    gq.biasN = bfold; gq.sBN = 768;
    gq.aShift = 256;
    gq.M = 4096; gq.N = 512; gq.K = 256;
    GemmP gv{};
    gv.A = Wf + 512 * 256; gv.lda = 256; gv.sA = 768L * 256;
    gv.B = qkv + 512; gv.ldb = 768; gv.sB = 4096L * 768;
    gv.O = vhT; gv.ldo = 4096; gv.sO = 256L * 4096;
    gv.biasM = bfold + 512; gv.sBM = 768;
    gv.M = 256; gv.N = 4096; gv.K = 256;
    projk<<<1536, 256, 0, stream>>>(gq, gv);
  }

  attn_lg<<<512, 256, 0, stream>>>(qk, vhT, khv, vhv, Wo, Wqkv, Wep1,
                                   ob, inb, ebc, oat, oatm, gcon, cnt);

  ep12<<<256, 256, 0, stream>>>(oat, Wcomb, Wep2, gcon, e2b, out);
}

// Round 12
// 325.067 us; speedup vs baseline: 1.3010x; 1.3010x over previous
//
#include <hip/hip_runtime.h>

#define DEV __device__ __forceinline__

typedef __attribute__((ext_vector_type(8))) short bfx8;
typedef __attribute__((ext_vector_type(4))) float fx4;

typedef __attribute__((address_space(3))) unsigned int as3_u32;
typedef const __attribute__((address_space(1))) unsigned int as1_u32c;

DEV void gl_lds16(const void* g, const void* l) {
  __builtin_amdgcn_global_load_lds((as1_u32c*)(unsigned long long)g,
                                   (as3_u32*)(unsigned long long)l, 16, 0, 0);
}

DEV short f2bf(float f) {
  unsigned u = __float_as_uint(f);
  u += 0x7fffu + ((u >> 16) & 1u);
  return (short)(u >> 16);
}
DEV float bf2f(short s) {
  return __uint_as_float(((unsigned)(unsigned short)s) << 16);
}
DEV float gelu_f(float x) { return 0.5f * x * (1.0f + erff(x * 0.70710678118654752f)); }

#define MFMA16(acc, a, b) (acc) = __builtin_amdgcn_mfma_f32_16x16x32_bf16((a), (b), (acc), 0, 0, 0)

// ---------------- prep: all weight conversions + text path + small precomputes (one dispatch) ----------------
struct PrepArgs {
  const float *w1, *inw, *ow, *tw, *e1w, *e2w, *txt, *w2, *e1b, *ob, *tb, *inb;
  short *W1bf, *Wqkv, *Wo, *Wtxt, *Wep1, *Wep2, *W2t, *Wcomb;
  float *ebc, *khv, *vhv;
};

__global__ __launch_bounds__(256) void prep(PrepArgs a) {
  __shared__ char shmem[34816];
  const int bid = (int)blockIdx.x;
  const int t = threadIdx.x;
  if (bid < 290) {
    const float* src; short* dst; int st;
    if (bid < 32)       { src = a.w1;  dst = a.W1bf; st = 0; }
    else if (bid < 128) { src = a.inw; dst = a.Wqkv; st = 32; }
    else if (bid < 160) { src = a.ow;  dst = a.Wo;   st = 128; }
    else if (bid < 224) { src = a.tw;  dst = a.Wtxt; st = 160; }
    else if (bid < 288) { src = a.e1w; dst = a.Wep1; st = 224; }
    else                { src = a.e2w; dst = a.Wep2; st = 288; }
    long i = ((long)(bid - st) * 256 + t) * 8;
    bfx8 o;
    #pragma unroll
    for (int j = 0; j < 8; ++j) o[j] = f2bf(src[i + j]);
    *(bfx8*)(dst + i) = o;
  } else if (bid < 1058) {
    int oc = (bid - 290) * 256 + t;
    const float* s = a.w2 + (long)oc * 9;
    float v[9];
    #pragma unroll
    for (int j = 0; j < 9; ++j) v[j] = s[j];
    #pragma unroll
    for (int tap = 0; tap < 9; ++tap)
      a.W2t[(long)tap * (768 * 256) + oc] = f2bf(v[tap]);
  } else if (bid < 1122) {
    int n = (bid - 1058) * 4 + (t >> 6);
    int lane = t & 63;
    float s = 0.0f;
    #pragma unroll
    for (int i = 0; i < 4; ++i) {
      int c = lane + 64 * i;
      s += a.ob[c] * a.e1w[(long)n * 512 + c];
    }
    #pragma unroll
    for (int off = 1; off < 64; off <<= 1) s += __shfl_xor(s, off);
    if (lane == 0) a.ebc[n] = a.e1b[n] + s;
  } else if (bid < 1130) {
    float* tmean = (float*)shmem;
    float* tfb = (float*)(shmem + 8192);
    const int b = bid - 1122;
    {
      int key = t >> 6, d0 = (t & 63) * 8;
      float s[8] = {};
      const float* src = a.txt + ((long)(b * 64 + key * 16)) * 512 + d0;
      for (int i = 0; i < 16; ++i) {
        fx4 v0 = *(const fx4*)(src + (long)i * 512);
        fx4 v1 = *(const fx4*)(src + (long)i * 512 + 4);
        #pragma unroll
        for (int j = 0; j < 4; ++j) { s[j] += v0[j]; s[4 + j] += v1[j]; }
      }
      #pragma unroll
      for (int j = 0; j < 8; ++j) tmean[key * 512 + d0 + j] = s[j] * (1.0f / 16.0f);
    }
    __syncthreads();
    {
      int n = t;
      float a0 = 0, a1 = 0, a2 = 0, a3 = 0;
      const float* wr = a.tw + (long)n * 512;
      for (int d = 0; d < 512; d += 4) {
        fx4 w = *(const fx4*)(wr + d);
        #pragma unroll
        for (int j = 0; j < 4; ++j) {
          float wf = w[j];
          a0 += tmean[0 * 512 + d + j] * wf;
          a1 += tmean[1 * 512 + d + j] * wf;
          a2 += tmean[2 * 512 + d + j] * wf;
          a3 += tmean[3 * 512 + d + j] * wf;
        }
      }
      float bias = a.tb[n];
      tfb[0 * 256 + n] = a0 + bias; tfb[1 * 256 + n] = a1 + bias;
      tfb[2 * 256 + n] = a2 + bias; tfb[3 * 256 + n] = a3 + bias;
    }
    __syncthreads();
    {
      int n = t;
      const float* wk = a.inw + (long)(256 + n) * 256;
      const float* wvp = a.inw + (long)(512 + n) * 256;
      float k0=0,k1=0,k2=0,k3=0,v0=0,v1=0,v2=0,v3=0;
      for (int d = 0; d < 256; d += 4) {
        fx4 wkv = *(const fx4*)(wk + d);
        fx4 wvv = *(const fx4*)(wvp + d);
        #pragma unroll
        for (int j = 0; j < 4; ++j) {
          float f0 = tfb[0*256+d+j], f1 = tfb[1*256+d+j], f2 = tfb[2*256+d+j], f3 = tfb[3*256+d+j];
          float kw = wkv[j], vw = wvv[j];
          k0 += f0*kw; k1 += f1*kw; k2 += f2*kw; k3 += f3*kw;
          v0 += f0*vw; v1 += f1*vw; v2 += f2*vw; v3 += f3*vw;
        }
      }
      float bk = a.inb[256+n], bv = a.inb[512+n];
      a.khv[(b*4+0)*256+n]=k0+bk; a.khv[(b*4+1)*256+n]=k1+bk;
      a.khv[(b*4+2)*256+n]=k2+bk; a.khv[(b*4+3)*256+n]=k3+bk;
      a.vhv[(b*4+0)*256+n]=v0+bv; a.vhv[(b*4+1)*256+n]=v1+bv;
      a.vhv[(b*4+2)*256+n]=v2+bv; a.vhv[(b*4+3)*256+n]=v3+bv;
    }
  } else {
    short* Bt = (short*)shmem;
    const int idx = bid - 1130;
    const int bx = idx & 3, by = idx >> 2;
    const int lane = t & 63, w = t >> 6;
    const int lg = lane >> 4, li = lane & 15;
    const int m0 = by * 64, n0 = bx * 64;
    for (int id2 = t; id2 < 64 * 256; id2 += 256) {
      int c = id2 >> 6, d = id2 & 63;
      Bt[d * 264 + c] = f2bf(a.ow[(long)c * 256 + n0 + d]);
    }
    __syncthreads();
    fx4 acc[4] = {};
    const float* aR = a.e1w + (long)(m0 + w * 16 + li) * 512 + lg * 8;
    for (int kc = 0; kc < 256; kc += 32) {
      fx4 lo = *(const fx4*)(aR + kc);
      fx4 hi = *(const fx4*)(aR + kc + 4);
      bfx8 av;
      av[0] = f2bf(lo[0]); av[1] = f2bf(lo[1]); av[2] = f2bf(lo[2]); av[3] = f2bf(lo[3]);
      av[4] = f2bf(hi[0]); av[5] = f2bf(hi[1]); av[6] = f2bf(hi[2]); av[7] = f2bf(hi[3]);
      #pragma unroll
      for (int ni = 0; ni < 4; ++ni) {
        bfx8 bv = *(const bfx8*)(&Bt[(ni * 16 + li) * 264 + kc + lg * 8]);
        MFMA16(acc[ni], av, bv);
      }
    }
    #pragma unroll
    for (int ni = 0; ni < 4; ++ni)
      #pragma unroll
      for (int r = 0; r < 4; ++r)
        a.Wcomb[(long)(m0 + w * 16 + 4 * lg + r) * 256 + n0 + ni * 16 + li] = f2bf(acc[ni][r]);
  }
}

// ---------------- fused transpose + conv1(1x1) + gelu (+ zero borders of xP) ----------------
DEV int axc(int p, int c) { return p * 260 + (c ^ (((p >> 2) & 7) << 2)); }

__global__ __launch_bounds__(256) void tc1(const float* fm, const short* W1bf,
                                           const float* b1, short* xP) {
  __shared__ float Af[64 * 260];
  const int lane = threadIdx.x & 63, wv = threadIdx.x >> 6;
  const int lg = lane >> 4, li = lane & 15;
  const int y = blockIdx.x & 63, b = blockIdx.x >> 6;
  const int t = threadIdx.x;
  short* dstP = xP + ((long)b * 66 * 66 + (long)(y + 1) * 66 + 1) * 256;
  const bfx8 z8 = {0, 0, 0, 0, 0, 0, 0, 0};

  if (t < 64) {
    if (t < 32) *(bfx8*)(dstP - 256 + t * 8) = z8;
    else        *(bfx8*)(dstP + 64 * 256 + (t - 32) * 8) = z8;
  }
  if (y == 0) {
    short* top = xP + (long)b * 66 * 66 * 256;
    for (int i = t; i < 2112; i += 256) *(bfx8*)(top + i * 8) = z8;
  }
  if (y == 63) {
    short* bot = xP + ((long)b * 66 * 66 + 65 * 66) * 256;
    for (int i = t; i < 2112; i += 256) *(bfx8*)(bot + i * 8) = z8;
  }

  const float* src = fm + (long)b * 256 * 4096 + y * 64;
  #pragma unroll
  for (int i = 0; i < 16; ++i) {
    int chunk = i * 256 + t;
    int c = chunk >> 4;
    int q = chunk & 15;
    fx4 v = *(const fx4*)(src + (long)c * 4096 + q * 4);
    #pragma unroll
    for (int j = 0; j < 4; ++j) Af[axc(q * 4 + j, c)] = v[j];
  }
  __syncthreads();

  fx4 acc[4][4] = {};
  const short* Bb = W1bf + (long)(wv * 64 + li) * 256 + lg * 8;
  for (int c0 = 0; c0 < 256; c0 += 32) {
    bfx8 af[4], bfr[4];
    #pragma unroll
    for (int mi = 0; mi < 4; ++mi) {
      int p = mi * 16 + li;
      fx4 lo = *(const fx4*)(&Af[axc(p, c0 + lg * 8)]);
      fx4 hi = *(const fx4*)(&Af[axc(p, c0 + lg * 8 + 4)]);
      bfx8 tt;
      tt[0] = f2bf(lo[0]); tt[1] = f2bf(lo[1]); tt[2] = f2bf(lo[2]); tt[3] = f2bf(lo[3]);
      tt[4] = f2bf(hi[0]); tt[5] = f2bf(hi[1]); tt[6] = f2bf(hi[2]); tt[7] = f2bf(hi[3]);
      af[mi] = tt;
    }
    #pragma unroll
    for (int ni = 0; ni < 4; ++ni) bfr[ni] = *(const bfx8*)(Bb + ni * 16 * 256 + c0);
    #pragma unroll
    for (int mi = 0; mi < 4; ++mi)
      #pragma unroll
      for (int ni = 0; ni < 4; ++ni) MFMA16(acc[mi][ni], af[mi], bfr[ni]);
  }

  #pragma unroll
  for (int mi = 0; mi < 4; ++mi)
    #pragma unroll
    for (int ni = 0; ni < 4; ++ni) {
      int col = wv * 64 + ni * 16 + li;
      float bias = b1[col];
      #pragma unroll
      for (int r = 0; r < 4; ++r) {
        int x = mi * 16 + 4 * lg + r;
        dstP[(long)x * 256 + col] = f2bf(gelu_f(acc[mi][ni][r] + bias));
      }
    }
}

// ---------------- 128x128 MFMA GEMM body, BK=64 ----------------
struct GemmP {
  const short* A; const short* B; void* O;
  const float* biasN; const float* biasM;
  long lda, ldb, ldo, sA, sB, sO;
  int M, N, K, outF32, act;
  int aShift;
  long sBN, sBM;
};

DEV void gemm_body64(const GemmP& g, int bx, int by, int bz) {
  __shared__ short As[2 * 128 * 32];
  __shared__ short Bs[2 * 128 * 32];
  const int lane = threadIdx.x & 63, wv = threadIdx.x >> 6;
  const int wm = wv >> 1, wn = wv & 1;
  const int lg = lane >> 4, li = lane & 15;
  const int m0 = by * 128, n0 = bx * 128, z = bz;
  const short* A = g.A + (long)z * g.sA + (long)(n0 >> 8) * g.aShift;
  const short* B = g.B + (long)z * g.sB;
  const int srow = wv * 16 + (lane >> 2);
  const int scol = (lane & 3) * 8;
  const short* pA0 = A + (long)(m0 + srow) * g.lda + scol;
  const short* pA1 = A + (long)(m0 + 64 + srow) * g.lda + scol;
  const short* pB0 = B + (long)(n0 + srow) * g.ldb + scol;
  const short* pB1 = B + (long)(n0 + 64 + srow) * g.ldb + scol;
  short* ldsA = As + wv * 512;
  short* ldsB = Bs + wv * 512;
  const short* aRd = As + (wm * 64 + li) * 32 + lg * 8;
  const short* bRd = Bs + (wn * 64 + li) * 32 + lg * 8;

  fx4 acc[4][4] = {};
  for (int kc = 0; kc < g.K; kc += 64) {
    gl_lds16(pA0 + kc, ldsA);
    gl_lds16(pA1 + kc, ldsA + 2048);
    gl_lds16(pA0 + kc + 32, ldsA + 4096);
    gl_lds16(pA1 + kc + 32, ldsA + 6144);
    gl_lds16(pB0 + kc, ldsB);
    gl_lds16(pB1 + kc, ldsB + 2048);
    gl_lds16(pB0 + kc + 32, ldsB + 4096);
    gl_lds16(pB1 + kc + 32, ldsB + 6144);
    __syncthreads();
    #pragma unroll
    for (int kk = 0; kk < 2; ++kk) {
      bfx8 af[4], bf[4];
      #pragma unroll
      for (int mi = 0; mi < 4; ++mi) af[mi] = *(const bfx8*)(aRd + kk * 4096 + mi * 16 * 32);
      #pragma unroll
      for (int ni = 0; ni < 4; ++ni) bf[ni] = *(const bfx8*)(bRd + kk * 4096 + ni * 16 * 32);
      #pragma unroll
      for (int mi = 0; mi < 4; ++mi)
        #pragma unroll
        for (int ni = 0; ni < 4; ++ni)
          MFMA16(acc[mi][ni], af[mi], bf[ni]);
    }
    __syncthreads();
  }

  #pragma unroll
  for (int mi = 0; mi < 4; ++mi)
    #pragma unroll
    for (int ni = 0; ni < 4; ++ni) {
      int col = n0 + wn * 64 + ni * 16 + li;
      int rowb = m0 + wm * 64 + mi * 16 + 4 * lg;
      float bn = g.biasN ? g.biasN[(long)z * g.sBN + col] : 0.0f;
      #pragma unroll
      for (int r = 0; r < 4; ++r) {
        int row = rowb + r;
        float v = acc[mi][ni][r] + bn;
        if (g.biasM) v += g.biasM[(long)z * g.sBM + row];
        if (g.act == 1) v = gelu_f(v);
        long oidx = (long)z * g.sO + (long)row * g.ldo + col;
        if (g.outF32) ((float*)g.O)[oidx] = v;
        else ((short*)g.O)[oidx] = f2bf(v);
      }
    }
}

// packed qk-proj (ids 0..1023) + v-proj (ids 1024..1535), XCD-swizzled
__global__ __launch_bounds__(256) void projk(GemmP gq, GemmP gv) {
  int bid = (int)blockIdx.x;
  int id = (bid & 7) * 192 + (bid >> 3);
  if (id < 1024) {
    int z = id >> 7, r = id & 127;
    gemm_body64(gq, r & 3, r >> 2, z);
  } else {
    int j = id - 1024;
    int z = j >> 6, r = j & 63;
    gemm_body64(gv, r & 31, r >> 5, z);
  }
}

// ---------------- conv2 3x3 implicit GEMM, BK=64, per-iteration offsets (round-10 form), XCD-swizzled ----------------
__global__ __launch_bounds__(256) void conv2g(const short* xP, const short* W2t,
                                              const float* b2, short* qkv, float* stats) {
  __shared__ short As[2 * 128 * 32];
  __shared__ short Bs[2 * 128 * 32];
  __shared__ float red[4][4];
  const int lane = threadIdx.x & 63, wv = threadIdx.x >> 6;
  const int wm = wv >> 1, wn = wv & 1;
  const int lg = lane >> 4, li = lane & 15;
  const int w = ((int)blockIdx.x & 7) * 192 + ((int)blockIdx.x >> 3);
  const int n0 = (w % 6) * 128;
  const int by = w / 6;
  const int b = by >> 5, ypair = by & 31;
  const short* xPb = xP + (long)b * 66 * 66 * 256;

  const int srow = wv * 16 + (lane >> 2);
  const int scol = (lane & 3) * 8;
  long baseA[2], baseB[2];
  #pragma unroll
  for (int j = 0; j < 2; ++j) {
    int r = j * 64 + srow;
    int yy = 2 * ypair + (r >> 6);
    int x = r & 63;
    baseA[j] = ((long)yy * 66 + x) * 256 + scol;
    baseB[j] = (long)(n0 + r) * 256 + scol;
  }
  short* ldsA = As + wv * 512;
  short* ldsB = Bs + wv * 512;
  const short* aRd = As + (wm * 64 + li) * 32 + lg * 8;
  const short* bRd = Bs + (wn * 64 + li) * 32 + lg * 8;

  fx4 acc[4][4] = {};
  for (int ks = 0; ks < 36; ++ks) {
    int tap = ks >> 2;
    int c0 = (ks & 3) * 64;
    int dy = tap / 3, dx = tap - dy * 3;
    long aoff = (long)(dy * 66 + dx) * 256 + c0;
    long boff = (long)tap * (768 * 256) + c0;
    gl_lds16(xPb + baseA[0] + aoff, ldsA);
    gl_lds16(xPb + baseA[1] + aoff, ldsA + 2048);
    gl_lds16(xPb + baseA[0] + aoff + 32, ldsA + 4096);
    gl_lds16(xPb + baseA[1] + aoff + 32, ldsA + 6144);
    gl_lds16(W2t + baseB[0] + boff, ldsB);
    gl_lds16(W2t + baseB[1] + boff, ldsB + 2048);
    gl_lds16(W2t + baseB[0] + boff + 32, ldsB + 4096);
    gl_lds16(W2t + baseB[1] + boff + 32, ldsB + 6144);
    __syncthreads();
    #pragma unroll
    for (int kk = 0; kk < 2; ++kk) {
      bfx8 af[4], bf[4];
      #pragma unroll
      for (int mi = 0; mi < 4; ++mi) af[mi] = *(const bfx8*)(aRd + kk * 4096 + mi * 16 * 32);
      #pragma unroll
      for (int ni = 0; ni < 4; ++ni) bf[ni] = *(const bfx8*)(bRd + kk * 4096 + ni * 16 * 32);
      #pragma unroll
      for (int mi = 0; mi < 4; ++mi)
        #pragma unroll
        for (int ni = 0; ni < 4; ++ni)
          MFMA16(acc[mi][ni], af[mi], bf[ni]);
    }
    __syncthreads();
  }

  const int g0 = n0 / 192;
  const int bnd = (g0 + 1) * 192;
  float sA = 0.0f, s2A = 0.0f, sB = 0.0f, s2B = 0.0f;
  const long prow0 = (long)b * 4096 + (long)ypair * 128 + wm * 64 + 4 * lg;
  #pragma unroll
  for (int ni = 0; ni < 4; ++ni) {
    int col = n0 + wn * 64 + ni * 16 + li;
    float bias = b2[col];
    bool inA = (col < bnd);
    #pragma unroll
    for (int mi = 0; mi < 4; ++mi) {
      long rb = prow0 + mi * 16;
      #pragma unroll
      for (int r = 0; r < 4; ++r) {
        float v = acc[mi][ni][r] + bias;
        if (inA) { sA += v; s2A += v * v; } else { sB += v; s2B += v * v; }
        qkv[(rb + r) * 768 + col] = f2bf(v);
      }
    }
  }
  #pragma unroll
  for (int off = 1; off < 64; off <<= 1) {
    sA += __shfl_xor(sA, off);  s2A += __shfl_xor(s2A, off);
    sB += __shfl_xor(sB, off);  s2B += __shfl_xor(s2B, off);
  }
  if (lane == 0) { red[wv][0] = sA; red[wv][1] = s2A; red[wv][2] = sB; red[wv][3] = s2B; }
  __syncthreads();
  if (threadIdx.x == 0) {
    float a1 = red[0][0] + red[1][0] + red[2][0] + red[3][0];
    float a2 = red[0][1] + red[1][1] + red[2][1] + red[3][1];
    atomicAdd(&stats[(b * 4 + g0) * 2], a1);
    atomicAdd(&stats[(b * 4 + g0) * 2 + 1], a2);
    if (bnd < n0 + 128) {
      float b1s = red[0][2] + red[1][2] + red[2][2] + red[3][2];
      float b2s = red[0][3] + red[1][3] + red[2][3] + red[3][3];
      atomicAdd(&stats[(b * 4 + g0 + 1) * 2], b1s);
      atomicAdd(&stats[(b * 4 + g0 + 1) * 2 + 1], b2s);
    }
  }
}

// fold GN affine into per-batch projection weights (stats finalized inline)
__global__ __launch_bounds__(256) void gn_fold(const float* stats, const float* gnw, const float* gnb,
                                               const float* inw, const float* inb,
                                               short* Wf, float* bfold) {
  const int lane = threadIdx.x & 63, wv = threadIdx.x >> 6;
  const int row = blockIdx.x * 4 + wv;
  const int b = row / 768, j = row - b * 768;
  const int cb = (j >> 8) << 8;
  const float nrm = 1.0f / (192.0f * 4096.0f);
  float part = 0.0f;
  #pragma unroll
  for (int i = 0; i < 4; ++i) {
    int c = lane + 64 * i;
    int cg = cb + c;
    int grp = cg / 192;
    float s1 = stats[(b * 4 + grp) * 2];
    float s2 = stats[(b * 4 + grp) * 2 + 1];
    float mu = s1 * nrm;
    float var = s2 * nrm - mu * mu;
    float rs = rsqrtf(var + 1e-5f);
    float s = rs * gnw[cg];
    float t = gnb[cg] - mu * s;
    float wv_ = inw[(long)j * 256 + c];
    Wf[(long)row * 256 + c] = f2bf(wv_ * s);
    part += t * wv_;
  }
  #pragma unroll
  for (int off = 1; off < 64; off <<= 1) part += __shfl_xor(part, off);
  if (lane == 0) bfold[row] = inb[j] + part;
}

// ---------------- local window attention (+ fused window mean -> oatm) ----------------
__global__ __launch_bounds__(256) void attn_local(const short* qk, const short* vhT,
                                                  short* oat, short* oatm) {
  __shared__ short Pl[4 * 64 * 72];
  const int lane = threadIdx.x & 63, h = threadIdx.x >> 6;
  const int lg = lane >> 4, li = lane & 15;
  const int bw = blockIdx.x;
  const int b = bw >> 6, wY = bw & 63;
  const long p0 = (long)bw * 64;

  bfx8 qf[4][2], kf[4][2];
  #pragma unroll
  for (int mi = 0; mi < 4; ++mi)
    #pragma unroll
    for (int ks = 0; ks < 2; ++ks) {
      qf[mi][ks] = *(const bfx8*)(qk + (p0 + 16 * mi + li) * 512 + h * 64 + 32 * ks + 8 * lg);
      kf[mi][ks] = *(const bfx8*)(qk + (p0 + 16 * mi + li) * 512 + 256 + h * 64 + 32 * ks + 8 * lg);
    }
  fx4 s[4][4] = {};
  #pragma unroll
  for (int mi = 0; mi < 4; ++mi)
    #pragma unroll
    for (int ni = 0; ni < 4; ++ni) {
      MFMA16(s[mi][ni], qf[mi][0], kf[ni][0]);
      MFMA16(s[mi][ni], qf[mi][1], kf[ni][1]);
    }
  #pragma unroll
  for (int mi = 0; mi < 4; ++mi)
    #pragma unroll
    for (int ni = 0; ni < 4; ++ni) s[mi][ni] *= 0.125f;

  #pragma unroll
  for (int mi = 0; mi < 4; ++mi)
    #pragma unroll
    for (int r = 0; r < 4; ++r) {
      float mx = fmaxf(fmaxf(s[mi][0][r], s[mi][1][r]), fmaxf(s[mi][2][r], s[mi][3][r]));
      for (int off = 1; off < 16; off <<= 1) mx = fmaxf(mx, __shfl_xor(mx, off));
      float e[4];
      float sum = 0.0f;
      #pragma unroll
      for (int ni = 0; ni < 4; ++ni) { e[ni] = expf(s[mi][ni][r] - mx); sum += e[ni]; }
      for (int off = 1; off < 16; off <<= 1) sum += __shfl_xor(sum, off);
      float inv = 1.0f / sum;
      int row = h * 64 + 16 * mi + 4 * lg + r;
      #pragma unroll
      for (int ni = 0; ni < 4; ++ni) Pl[row * 72 + 16 * ni + li] = f2bf(e[ni] * inv);
    }
  __syncthreads();

  fx4 o[4][4] = {};
  #pragma unroll
  for (int ks = 0; ks < 2; ++ks) {
    bfx8 pf[4], vf[4];
    #pragma unroll
    for (int mi = 0; mi < 4; ++mi)
      pf[mi] = *(const bfx8*)(&Pl[(h * 64 + 16 * mi + li) * 72 + 32 * ks + 8 * lg]);
    #pragma unroll
    for (int ni = 0; ni < 4; ++ni)
      vf[ni] = *(const bfx8*)(vhT + ((long)(b * 256 + h * 64 + 16 * ni + li)) * 4096 + wY * 64 + 32 * ks + 8 * lg);
    #pragma unroll
    for (int mi = 0; mi < 4; ++mi)
      #pragma unroll
      for (int ni = 0; ni < 4; ++ni) MFMA16(o[mi][ni], pf[mi], vf[ni]);
  }
  #pragma unroll
  for (int mi = 0; mi < 4; ++mi)
    #pragma unroll
    for (int ni = 0; ni < 4; ++ni)
      #pragma unroll
      for (int r = 0; r < 4; ++r)
        oat[(p0 + 16 * mi + 4 * lg + r) * 256 + h * 64 + 16 * ni + li] = f2bf(o[mi][ni][r]);

  #pragma unroll
  for (int ni = 0; ni < 4; ++ni) {
    float s2 = 0.0f;
    #pragma unroll
    for (int mi = 0; mi < 4; ++mi)
      #pragma unroll
      for (int r = 0; r < 4; ++r) s2 += o[mi][ni][r];
    s2 += __shfl_xor(s2, 16);
    s2 += __shfl_xor(s2, 32);
    if (lg == 0)
      oatm[(long)bw * 256 + h * 64 + 16 * ni + li] = f2bf(s2 * (1.0f / 64.0f));
  }
}

// ---------------- per-batch global chain (MFMA-batched over 64 windows): oatm -> gcon ----------------
#define GP 272

DEV void mm_stage(const short* srcA, const short* Bw, long ldb, const float* biasN,
                  short* dstL, float* dstG, int wv, int lg, int li) {
  fx4 acc[4][4] = {};
  const short* aRd = srcA + li * GP + lg * 8;
  const short* bR = Bw + (long)(wv * 64 + li) * ldb + lg * 8;
  for (int kc = 0; kc < 256; kc += 32) {
    bfx8 af[4], bf[4];
    #pragma unroll
    for (int mi = 0; mi < 4; ++mi) af[mi] = *(const bfx8*)(aRd + mi * 16 * GP + kc);
    #pragma unroll
    for (int ni = 0; ni < 4; ++ni) bf[ni] = *(const bfx8*)(bR + (long)ni * 16 * ldb + kc);
    #pragma unroll
    for (int mi = 0; mi < 4; ++mi)
      #pragma unroll
      for (int ni = 0; ni < 4; ++ni) MFMA16(acc[mi][ni], af[mi], bf[ni]);
  }
  #pragma unroll
  for (int mi = 0; mi < 4; ++mi)
    #pragma unroll
    for (int ni = 0; ni < 4; ++ni) {
      int col = wv * 64 + ni * 16 + li;
      float bn = biasN[col];
      #pragma unroll
      for (int r = 0; r < 4; ++r) {
        int row = mi * 16 + 4 * lg + r;
        float v = acc[mi][ni][r] + bn;
        if (dstL) dstL[row * GP + col] = f2bf(v);
        else dstG[(long)row * 256 + col] = v;
      }
    }
}

__global__ __launch_bounds__(256) void globk2(
    const short* oatm, const float* khv, const float* vhv,
    const short* Wo, const short* Wqkv, const short* Wep1,
    const float* ob, const float* inb, const float* ebc,
    float* gcon) {
  __shared__ short bufA[64 * GP];
  __shared__ short bufB[64 * GP];
  __shared__ float kh_s[4][256];
  __shared__ float vh_s[4][256];
  const int t = threadIdx.x;
  const int lane = t & 63, wv = t >> 6;
  const int lg = lane >> 4, li = lane & 15;
  const int b = blockIdx.x;

  {
    #pragma unroll
    for (int i = 0; i < 8; ++i) {
      int chunk = i * 256 + t;
      int row = chunk >> 5, colc = (chunk & 31) * 8;
      *(bfx8*)(bufA + row * GP + colc) =
          *(const bfx8*)(oatm + ((long)(b * 64 + row)) * 256 + colc);
    }
    #pragma unroll
    for (int key = 0; key < 4; ++key) {
      kh_s[key][t] = khv[(long)(b * 4 + key) * 256 + t];
      vh_s[key][t] = vhv[(long)(b * 4 + key) * 256 + t];
    }
  }
  __syncthreads();
  mm_stage(bufA, Wo, 256, ob, bufB, nullptr, wv, lg, li);
  __syncthreads();
  mm_stage(bufB, Wqkv, 256, inb, bufA, nullptr, wv, lg, li);
  __syncthreads();
  {
    int p = t >> 2, h = t & 3;
    const short* qr = bufA + p * GP + h * 64;
    float sc[4];
    #pragma unroll
    for (int key = 0; key < 4; ++key) {
      float s = 0.0f;
      for (int d = 0; d < 64; d += 8) {
        bfx8 q8 = *(const bfx8*)(qr + d);
        #pragma unroll
        for (int j = 0; j < 8; ++j) s += bf2f(q8[j]) * kh_s[key][h * 64 + d + j];
      }
      sc[key] = s * 0.125f;
    }
    float mx = fmaxf(fmaxf(sc[0], sc[1]), fmaxf(sc[2], sc[3]));
    float e0 = expf(sc[0]-mx), e1 = expf(sc[1]-mx), e2 = expf(sc[2]-mx), e3 = expf(sc[3]-mx);
    float inv = 1.0f / (e0 + e1 + e2 + e3);
    e0 *= inv; e1 *= inv; e2 *= inv; e3 *= inv;
    short* orow = bufB + p * GP + h * 64;
    for (int d = 0; d < 64; ++d) {
      float o = e0*vh_s[0][h*64+d] + e1*vh_s[1][h*64+d] + e2*vh_s[2][h*64+d] + e3*vh_s[3][h*64+d];
      orow[d] = f2bf(o);
    }
  }
  __syncthreads();
  mm_stage(bufB, Wo, 256, ob, bufA, nullptr, wv, lg, li);
  __syncthreads();
  mm_stage(bufA, Wep1 + 256, 512, ebc, nullptr, gcon + (long)b * 64 * 256, wv, lg, li);
}

// ---------------- fused ep1 + ep2 + sigmoid: oat -> out (BK=64 staging) ----------------
__global__ __launch_bounds__(256) void ep12(const short* oat, const short* Wcomb,
                                            const short* Wep2, const float* gcon,
                                            const float* e2b, float* out) {
  __shared__ short As[2 * 128 * 32];
  __shared__ short Bs[2 * 128 * 32];
  __shared__ short hl[128 * 140];
  const int lane = threadIdx.x & 63, wv = threadIdx.x >> 6;
  const int wm = wv >> 1, wn = wv & 1;
  const int lg = lane >> 4, li = lane & 15;
  const int m0 = (int)blockIdx.x * 128;
  const int srow = wv * 16 + (lane >> 2);
  const int scol = (lane & 3) * 8;
  const short* pA0 = oat + (long)(m0 + srow) * 256 + scol;
  const short* pA1 = oat + (long)(m0 + 64 + srow) * 256 + scol;
  short* ldsA = As + wv * 512;
  short* ldsB = Bs + wv * 512;
  const short* aRd = As + (wm * 64 + li) * 32 + lg * 8;
  const short* bRd = Bs + (wn * 64 + li) * 32 + lg * 8;

  fx4 eacc[2] = {};
  for (int half = 0; half < 2; ++half) {
    const short* B = Wcomb + (long)(half * 128) * 256;
    const short* pB0 = B + (long)srow * 256 + scol;
    const short* pB1 = B + (long)(64 + srow) * 256 + scol;
    fx4 acc[4][4] = {};
    for (int kc = 0; kc < 256; kc += 64) {
      gl_lds16(pA0 + kc, ldsA);
      gl_lds16(pA1 + kc, ldsA + 2048);
      gl_lds16(pA0 + kc + 32, ldsA + 4096);
      gl_lds16(pA1 + kc + 32, ldsA + 6144);
      gl_lds16(pB0 + kc, ldsB);
      gl_lds16(pB1 + kc, ldsB + 2048);
      gl_lds16(pB0 + kc + 32, ldsB + 4096);
      gl_lds16(pB1 + kc + 32, ldsB + 6144);
      __syncthreads();
      #pragma unroll
      for (int kk = 0; kk < 2; ++kk) {
        bfx8 af[4], bf[4];
        #pragma unroll
        for (int mi = 0; mi < 4; ++mi) af[mi] = *(const bfx8*)(aRd + kk * 4096 + mi * 16 * 32);
        #pragma unroll
        for (int ni = 0; ni < 4; ++ni) bf[ni] = *(const bfx8*)(bRd + kk * 4096 + ni * 16 * 32);
        #pragma unroll
        for (int mi = 0; mi < 4; ++mi)
          #pragma unroll
          for (int ni = 0; ni < 4; ++ni)
            MFMA16(acc[mi][ni], af[mi], bf[ni]);
      }
      __syncthreads();
    }
    #pragma unroll
    for (int mi = 0; mi < 4; ++mi)
      #pragma unroll
      for (int ni = 0; ni < 4; ++ni) {
        int coll = wn * 64 + ni * 16 + li;
        int colg = half * 128 + coll;
        #pragma unroll
        for (int r = 0; r < 4; ++r) {
          int rowl = wm * 64 + mi * 16 + 4 * lg + r;
          float v = acc[mi][ni][r] + gcon[(long)((m0 + rowl) >> 6) * 256 + colg];
          hl[rowl * 140 + coll] = f2bf(gelu_f(v));
        }
      }
    __syncthreads();
    #pragma unroll
    for (int kc = 0; kc < 128; kc += 32) {
      bfx8 bf2v = *(const bfx8*)(Wep2 + (long)li * 256 + half * 128 + kc + lg * 8);
      #pragma unroll
      for (int mi = 0; mi < 2; ++mi) {
        bfx8 af = *(const bfx8*)(hl + (wv * 32 + mi * 16 + li) * 140 + kc + lg * 8);
        MFMA16(eacc[mi], af, bf2v);
      }
    }
    __syncthreads();
  }
  #pragma unroll
  for (int mi = 0; mi < 2; ++mi)
    #pragma unroll
    for (int r = 0; r < 4; ++r) {
      int row = m0 + wv * 32 + mi * 16 + 4 * lg + r;
      out[(long)row * 16 + li] = 1.0f / (1.0f + expf(-(eacc[mi][r] + e2b[li])));
    }
}

// ---------------- host ----------------
extern "C" void kernel_launch(void* const* d_in, const int* in_sizes, int n_in,
                              void* d_out, int out_size, void* d_ws, size_t ws_size,
                              hipStream_t stream) {
  (void)in_sizes; (void)n_in; (void)out_size; (void)ws_size;
  const float* fm  = (const float*)d_in[0];
  const float* txt = (const float*)d_in[1];
  const float* w1  = (const float*)d_in[2];
  const float* b1  = (const float*)d_in[3];
  const float* w2  = (const float*)d_in[4];
  const float* b2  = (const float*)d_in[5];
  const float* gnw = (const float*)d_in[6];
  const float* gnb = (const float*)d_in[7];
  const float* inw = (const float*)d_in[8];
  const float* inb = (const float*)d_in[9];
  const float* ow  = (const float*)d_in[10];
  const float* ob  = (const float*)d_in[11];
  const float* tw  = (const float*)d_in[12];
  const float* tb  = (const float*)d_in[13];
  const float* e1w = (const float*)d_in[14];
  const float* e1b = (const float*)d_in[15];
  const float* e2w = (const float*)d_in[16];
  const float* e2b = (const float*)d_in[17];
  float* out = (float*)d_out;

  char* base = (char*)d_ws;
  size_t off = 0;
  auto alloc = [&](size_t bytes) -> char* {
    char* r = base + off;
    off = (off + bytes + 255) & ~(size_t)255;
    return r;
  };
  short* W1bf = (short*)alloc(256 * 256 * 2);
  short* W2t  = (short*)alloc((size_t)9 * 768 * 256 * 2);
  short* Wqkv = (short*)alloc(768 * 256 * 2);
  short* Wo   = (short*)alloc(256 * 256 * 2);
  short* Wcomb= (short*)alloc(256 * 256 * 2);
  float* ebc  = (float*)alloc(256 * 4);
  short* Wtxt = (short*)alloc(256 * 512 * 2);
  short* Wep1 = (short*)alloc(256 * 512 * 2);
  short* Wep2 = (short*)alloc(16 * 256 * 2);
  short* xP   = (short*)alloc((size_t)8 * 66 * 66 * 256 * 2);
  short* qkv  = (short*)alloc((size_t)8 * 4096 * 768 * 2);
  float* stats= (float*)alloc(64 * 4);
  short* Wf   = (short*)alloc((size_t)8 * 768 * 256 * 2);
  float* bfold= (float*)alloc((size_t)8 * 768 * 4);
  short* qk   = (short*)alloc((size_t)32768 * 512 * 2);
  short* vhT  = (short*)alloc((size_t)8 * 4096 * 256 * 2);
  short* oat  = (short*)alloc((size_t)8 * 4096 * 256 * 2);
  short* oatm = (short*)alloc(512 * 256 * 2);
  float* khv  = (float*)alloc(8 * 4 * 256 * 4);
  float* vhv  = (float*)alloc(8 * 4 * 256 * 4);
  float* gcon = (float*)alloc(512 * 256 * 4);

  hipMemsetAsync(stats, 0, 64 * 4, stream);

  PrepArgs pa;
  pa.w1 = w1; pa.inw = inw; pa.ow = ow; pa.tw = tw; pa.e1w = e1w; pa.e2w = e2w;
  pa.txt = txt; pa.w2 = w2; pa.e1b = e1b; pa.ob = ob; pa.tb = tb; pa.inb = inb;
  pa.W1bf = W1bf; pa.Wqkv = Wqkv; pa.Wo = Wo; pa.Wtxt = Wtxt; pa.Wep1 = Wep1;
  pa.Wep2 = Wep2; pa.W2t = W2t; pa.Wcomb = Wcomb;
  pa.ebc = ebc; pa.khv = khv; pa.vhv = vhv;
  prep<<<1146, 256, 0, stream>>>(pa);

  tc1<<<512, 256, 0, stream>>>(fm, W1bf, b1, xP);

  conv2g<<<1536, 256, 0, stream>>>(xP, W2t, b2, qkv, stats);

  gn_fold<<<1536, 256, 0, stream>>>(stats, gnw, gnb, inw, inb, Wf, bfold);

  { // packed qk + v projections
    GemmP gq{};
    gq.A = qkv; gq.lda = 768; gq.sA = 4096L * 768;
    gq.B = Wf; gq.ldb = 256; gq.sB = 768L * 256;
    gq.O = qk; gq.ldo = 512; gq.sO = 4096L * 512;
    gq.biasN = bfold; gq.sBN = 768;
    gq.aShift = 256;
    gq.M = 4096; gq.N = 512; gq.K = 256;
    GemmP gv{};
    gv.A = Wf + 512 * 256; gv.lda = 256; gv.sA = 768L * 256;
    gv.B = qkv + 512; gv.ldb = 768; gv.sB = 4096L * 768;
    gv.O = vhT; gv.ldo = 4096; gv.sO = 256L * 4096;
    gv.biasM = bfold + 512; gv.sBM = 768;
    gv.M = 256; gv.N = 4096; gv.K = 256;
    projk<<<1536, 256, 0, stream>>>(gq, gv);
  }

  attn_local<<<512, 256, 0, stream>>>(qk, vhT, oat, oatm);

  globk2<<<8, 256, 0, stream>>>(oatm, khv, vhv, Wo, Wqkv, Wep1, ob, inb, ebc, gcon);

  ep12<<<256, 256, 0, stream>>>(oat, Wcomb, Wep2, gcon, e2b, out);
}

// Round 13
// 317.929 us; speedup vs baseline: 1.3303x; 1.0225x over previous
//
#include <hip/hip_runtime.h>

#define DEV __device__ __forceinline__

typedef __attribute__((ext_vector_type(8))) short bfx8;
typedef __attribute__((ext_vector_type(4))) float fx4;

typedef __attribute__((address_space(3))) unsigned int as3_u32;
typedef const __attribute__((address_space(1))) unsigned int as1_u32c;

DEV void gl_lds16(const void* g, const void* l) {
  __builtin_amdgcn_global_load_lds((as1_u32c*)(unsigned long long)g,
                                   (as3_u32*)(unsigned long long)l, 16, 0, 0);
}

DEV short f2bf(float f) {
  unsigned u = __float_as_uint(f);
  u += 0x7fffu + ((u >> 16) & 1u);
  return (short)(u >> 16);
}
DEV float bf2f(short s) {
  return __uint_as_float(((unsigned)(unsigned short)s) << 16);
}
DEV float gelu_f(float x) { return 0.5f * x * (1.0f + erff(x * 0.70710678118654752f)); }

#define MFMA16(acc, a, b) (acc) = __builtin_amdgcn_mfma_f32_16x16x32_bf16((a), (b), (acc), 0, 0, 0)

// ---------------- prep: all weight conversions + text path + small precomputes (one dispatch) ----------------
struct PrepArgs {
  const float *w1, *inw, *ow, *tw, *e1w, *e2w, *txt, *w2, *e1b, *ob, *tb, *inb;
  short *W1bf, *Wqkv, *Wo, *Wtxt, *Wep1, *Wep2, *W2t, *Wcomb;
  float *ebc, *khv, *vhv;
};

__global__ __launch_bounds__(256) void prep(PrepArgs a) {
  __shared__ char shmem[34816];
  const int bid = (int)blockIdx.x;
  const int t = threadIdx.x;
  if (bid < 290) {
    const float* src; short* dst; int st;
    if (bid < 32)       { src = a.w1;  dst = a.W1bf; st = 0; }
    else if (bid < 128) { src = a.inw; dst = a.Wqkv; st = 32; }
    else if (bid < 160) { src = a.ow;  dst = a.Wo;   st = 128; }
    else if (bid < 224) { src = a.tw;  dst = a.Wtxt; st = 160; }
    else if (bid < 288) { src = a.e1w; dst = a.Wep1; st = 224; }
    else                { src = a.e2w; dst = a.Wep2; st = 288; }
    long i = ((long)(bid - st) * 256 + t) * 8;
    bfx8 o;
    #pragma unroll
    for (int j = 0; j < 8; ++j) o[j] = f2bf(src[i + j]);
    *(bfx8*)(dst + i) = o;
  } else if (bid < 1058) {
    int oc = (bid - 290) * 256 + t;
    const float* s = a.w2 + (long)oc * 9;
    float v[9];
    #pragma unroll
    for (int j = 0; j < 9; ++j) v[j] = s[j];
    #pragma unroll
    for (int tap = 0; tap < 9; ++tap)
      a.W2t[(long)tap * (768 * 256) + oc] = f2bf(v[tap]);
  } else if (bid < 1122) {
    int n = (bid - 1058) * 4 + (t >> 6);
    int lane = t & 63;
    float s = 0.0f;
    #pragma unroll
    for (int i = 0; i < 4; ++i) {
      int c = lane + 64 * i;
      s += a.ob[c] * a.e1w[(long)n * 512 + c];
    }
    #pragma unroll
    for (int off = 1; off < 64; off <<= 1) s += __shfl_xor(s, off);
    if (lane == 0) a.ebc[n] = a.e1b[n] + s;
  } else if (bid < 1130) {
    float* tmean = (float*)shmem;
    float* tfb = (float*)(shmem + 8192);
    const int b = bid - 1122;
    {
      int key = t >> 6, d0 = (t & 63) * 8;
      float s[8] = {};
      const float* src = a.txt + ((long)(b * 64 + key * 16)) * 512 + d0;
      for (int i = 0; i < 16; ++i) {
        fx4 v0 = *(const fx4*)(src + (long)i * 512);
        fx4 v1 = *(const fx4*)(src + (long)i * 512 + 4);
        #pragma unroll
        for (int j = 0; j < 4; ++j) { s[j] += v0[j]; s[4 + j] += v1[j]; }
      }
      #pragma unroll
      for (int j = 0; j < 8; ++j) tmean[key * 512 + d0 + j] = s[j] * (1.0f / 16.0f);
    }
    __syncthreads();
    {
      int n = t;
      float a0 = 0, a1 = 0, a2 = 0, a3 = 0;
      const float* wr = a.tw + (long)n * 512;
      for (int d = 0; d < 512; d += 4) {
        fx4 w = *(const fx4*)(wr + d);
        #pragma unroll
        for (int j = 0; j < 4; ++j) {
          float wf = w[j];
          a0 += tmean[0 * 512 + d + j] * wf;
          a1 += tmean[1 * 512 + d + j] * wf;
          a2 += tmean[2 * 512 + d + j] * wf;
          a3 += tmean[3 * 512 + d + j] * wf;
        }
      }
      float bias = a.tb[n];
      tfb[0 * 256 + n] = a0 + bias; tfb[1 * 256 + n] = a1 + bias;
      tfb[2 * 256 + n] = a2 + bias; tfb[3 * 256 + n] = a3 + bias;
    }
    __syncthreads();
    {
      int n = t;
      const float* wk = a.inw + (long)(256 + n) * 256;
      const float* wvp = a.inw + (long)(512 + n) * 256;
      float k0=0,k1=0,k2=0,k3=0,v0=0,v1=0,v2=0,v3=0;
      for (int d = 0; d < 256; d += 4) {
        fx4 wkv = *(const fx4*)(wk + d);
        fx4 wvv = *(const fx4*)(wvp + d);
        #pragma unroll
        for (int j = 0; j < 4; ++j) {
          float f0 = tfb[0*256+d+j], f1 = tfb[1*256+d+j], f2 = tfb[2*256+d+j], f3 = tfb[3*256+d+j];
          float kw = wkv[j], vw = wvv[j];
          k0 += f0*kw; k1 += f1*kw; k2 += f2*kw; k3 += f3*kw;
          v0 += f0*vw; v1 += f1*vw; v2 += f2*vw; v3 += f3*vw;
        }
      }
      float bk = a.inb[256+n], bv = a.inb[512+n];
      a.khv[(b*4+0)*256+n]=k0+bk; a.khv[(b*4+1)*256+n]=k1+bk;
      a.khv[(b*4+2)*256+n]=k2+bk; a.khv[(b*4+3)*256+n]=k3+bk;
      a.vhv[(b*4+0)*256+n]=v0+bv; a.vhv[(b*4+1)*256+n]=v1+bv;
      a.vhv[(b*4+2)*256+n]=v2+bv; a.vhv[(b*4+3)*256+n]=v3+bv;
    }
  } else {
    short* Bt = (short*)shmem;
    const int idx = bid - 1130;
    const int bx = idx & 3, by = idx >> 2;
    const int lane = t & 63, w = t >> 6;
    const int lg = lane >> 4, li = lane & 15;
    const int m0 = by * 64, n0 = bx * 64;
    for (int id2 = t; id2 < 64 * 256; id2 += 256) {
      int c = id2 >> 6, d = id2 & 63;
      Bt[d * 264 + c] = f2bf(a.ow[(long)c * 256 + n0 + d]);
    }
    __syncthreads();
    fx4 acc[4] = {};
    const float* aR = a.e1w + (long)(m0 + w * 16 + li) * 512 + lg * 8;
    for (int kc = 0; kc < 256; kc += 32) {
      fx4 lo = *(const fx4*)(aR + kc);
      fx4 hi = *(const fx4*)(aR + kc + 4);
      bfx8 av;
      av[0] = f2bf(lo[0]); av[1] = f2bf(lo[1]); av[2] = f2bf(lo[2]); av[3] = f2bf(lo[3]);
      av[4] = f2bf(hi[0]); av[5] = f2bf(hi[1]); av[6] = f2bf(hi[2]); av[7] = f2bf(hi[3]);
      #pragma unroll
      for (int ni = 0; ni < 4; ++ni) {
        bfx8 bv = *(const bfx8*)(&Bt[(ni * 16 + li) * 264 + kc + lg * 8]);
        MFMA16(acc[ni], av, bv);
      }
    }
    #pragma unroll
    for (int ni = 0; ni < 4; ++ni)
      #pragma unroll
      for (int r = 0; r < 4; ++r)
        a.Wcomb[(long)(m0 + w * 16 + 4 * lg + r) * 256 + n0 + ni * 16 + li] = f2bf(acc[ni][r]);
  }
}

// ---------------- fused transpose + conv1(1x1) + gelu (+ zero borders of xP) ----------------
DEV int axc(int p, int c) { return p * 260 + (c ^ (((p >> 2) & 7) << 2)); }

__global__ __launch_bounds__(256) void tc1(const float* fm, const short* W1bf,
                                           const float* b1, short* xP) {
  __shared__ float Af[64 * 260];
  const int lane = threadIdx.x & 63, wv = threadIdx.x >> 6;
  const int lg = lane >> 4, li = lane & 15;
  const int y = blockIdx.x & 63, b = blockIdx.x >> 6;
  const int t = threadIdx.x;
  short* dstP = xP + ((long)b * 66 * 66 + (long)(y + 1) * 66 + 1) * 256;
  const bfx8 z8 = {0, 0, 0, 0, 0, 0, 0, 0};

  if (t < 64) {
    if (t < 32) *(bfx8*)(dstP - 256 + t * 8) = z8;
    else        *(bfx8*)(dstP + 64 * 256 + (t - 32) * 8) = z8;
  }
  if (y == 0) {
    short* top = xP + (long)b * 66 * 66 * 256;
    for (int i = t; i < 2112; i += 256) *(bfx8*)(top + i * 8) = z8;
  }
  if (y == 63) {
    short* bot = xP + ((long)b * 66 * 66 + 65 * 66) * 256;
    for (int i = t; i < 2112; i += 256) *(bfx8*)(bot + i * 8) = z8;
  }

  const float* src = fm + (long)b * 256 * 4096 + y * 64;
  #pragma unroll
  for (int i = 0; i < 16; ++i) {
    int chunk = i * 256 + t;
    int c = chunk >> 4;
    int q = chunk & 15;
    fx4 v = *(const fx4*)(src + (long)c * 4096 + q * 4);
    #pragma unroll
    for (int j = 0; j < 4; ++j) Af[axc(q * 4 + j, c)] = v[j];
  }
  __syncthreads();

  fx4 acc[4][4] = {};
  const short* Bb = W1bf + (long)(wv * 64 + li) * 256 + lg * 8;
  for (int c0 = 0; c0 < 256; c0 += 32) {
    bfx8 af[4], bfr[4];
    #pragma unroll
    for (int mi = 0; mi < 4; ++mi) {
      int p = mi * 16 + li;
      fx4 lo = *(const fx4*)(&Af[axc(p, c0 + lg * 8)]);
      fx4 hi = *(const fx4*)(&Af[axc(p, c0 + lg * 8 + 4)]);
      bfx8 tt;
      tt[0] = f2bf(lo[0]); tt[1] = f2bf(lo[1]); tt[2] = f2bf(lo[2]); tt[3] = f2bf(lo[3]);
      tt[4] = f2bf(hi[0]); tt[5] = f2bf(hi[1]); tt[6] = f2bf(hi[2]); tt[7] = f2bf(hi[3]);
      af[mi] = tt;
    }
    #pragma unroll
    for (int ni = 0; ni < 4; ++ni) bfr[ni] = *(const bfx8*)(Bb + ni * 16 * 256 + c0);
    #pragma unroll
    for (int mi = 0; mi < 4; ++mi)
      #pragma unroll
      for (int ni = 0; ni < 4; ++ni) MFMA16(acc[mi][ni], af[mi], bfr[ni]);
  }

  #pragma unroll
  for (int mi = 0; mi < 4; ++mi)
    #pragma unroll
    for (int ni = 0; ni < 4; ++ni) {
      int col = wv * 64 + ni * 16 + li;
      float bias = b1[col];
      #pragma unroll
      for (int r = 0; r < 4; ++r) {
        int x = mi * 16 + 4 * lg + r;
        dstP[(long)x * 256 + col] = f2bf(gelu_f(acc[mi][ni][r] + bias));
      }
    }
}

// ---------------- 128x128 MFMA GEMM body, BK=64 ----------------
struct GemmP {
  const short* A; const short* B; void* O;
  const float* biasN; const float* biasM;
  long lda, ldb, ldo, sA, sB, sO;
  int M, N, K, outF32, act;
  int aShift;
  long sBN, sBM;
};

DEV void gemm_body64(const GemmP& g, int bx, int by, int bz) {
  __shared__ short As[2 * 128 * 32];
  __shared__ short Bs[2 * 128 * 32];
  const int lane = threadIdx.x & 63, wv = threadIdx.x >> 6;
  const int wm = wv >> 1, wn = wv & 1;
  const int lg = lane >> 4, li = lane & 15;
  const int m0 = by * 128, n0 = bx * 128, z = bz;
  const short* A = g.A + (long)z * g.sA + (long)(n0 >> 8) * g.aShift;
  const short* B = g.B + (long)z * g.sB;
  const int srow = wv * 16 + (lane >> 2);
  const int scol = (lane & 3) * 8;
  const short* pA0 = A + (long)(m0 + srow) * g.lda + scol;
  const short* pA1 = A + (long)(m0 + 64 + srow) * g.lda + scol;
  const short* pB0 = B + (long)(n0 + srow) * g.ldb + scol;
  const short* pB1 = B + (long)(n0 + 64 + srow) * g.ldb + scol;
  short* ldsA = As + wv * 512;
  short* ldsB = Bs + wv * 512;
  const short* aRd = As + (wm * 64 + li) * 32 + lg * 8;
  const short* bRd = Bs + (wn * 64 + li) * 32 + lg * 8;

  fx4 acc[4][4] = {};
  for (int kc = 0; kc < g.K; kc += 64) {
    gl_lds16(pA0 + kc, ldsA);
    gl_lds16(pA1 + kc, ldsA + 2048);
    gl_lds16(pA0 + kc + 32, ldsA + 4096);
    gl_lds16(pA1 + kc + 32, ldsA + 6144);
    gl_lds16(pB0 + kc, ldsB);
    gl_lds16(pB1 + kc, ldsB + 2048);
    gl_lds16(pB0 + kc + 32, ldsB + 4096);
    gl_lds16(pB1 + kc + 32, ldsB + 6144);
    __syncthreads();
    #pragma unroll
    for (int kk = 0; kk < 2; ++kk) {
      bfx8 af[4], bf[4];
      #pragma unroll
      for (int mi = 0; mi < 4; ++mi) af[mi] = *(const bfx8*)(aRd + kk * 4096 + mi * 16 * 32);
      #pragma unroll
      for (int ni = 0; ni < 4; ++ni) bf[ni] = *(const bfx8*)(bRd + kk * 4096 + ni * 16 * 32);
      #pragma unroll
      for (int mi = 0; mi < 4; ++mi)
        #pragma unroll
        for (int ni = 0; ni < 4; ++ni)
          MFMA16(acc[mi][ni], af[mi], bf[ni]);
    }
    __syncthreads();
  }

  #pragma unroll
  for (int mi = 0; mi < 4; ++mi)
    #pragma unroll
    for (int ni = 0; ni < 4; ++ni) {
      int col = n0 + wn * 64 + ni * 16 + li;
      int rowb = m0 + wm * 64 + mi * 16 + 4 * lg;
      float bn = g.biasN ? g.biasN[(long)z * g.sBN + col] : 0.0f;
      #pragma unroll
      for (int r = 0; r < 4; ++r) {
        int row = rowb + r;
        float v = acc[mi][ni][r] + bn;
        if (g.biasM) v += g.biasM[(long)z * g.sBM + row];
        if (g.act == 1) v = gelu_f(v);
        long oidx = (long)z * g.sO + (long)row * g.ldo + col;
        if (g.outF32) ((float*)g.O)[oidx] = v;
        else ((short*)g.O)[oidx] = f2bf(v);
      }
    }
}

// packed qk-proj (ids 0..1023) + v-proj (ids 1024..1535), XCD-swizzled
__global__ __launch_bounds__(256) void projk(GemmP gq, GemmP gv) {
  int bid = (int)blockIdx.x;
  int id = (bid & 7) * 192 + (bid >> 3);
  if (id < 1024) {
    int z = id >> 7, r = id & 127;
    gemm_body64(gq, r & 3, r >> 2, z);
  } else {
    int j = id - 1024;
    int z = j >> 6, r = j & 63;
    gemm_body64(gv, r & 31, r >> 5, z);
  }
}

// ---------------- conv2 3x3 implicit GEMM, BK=64, per-iteration offsets, XCD-swizzled ----------------
__global__ __launch_bounds__(256) void conv2g(const short* xP, const short* W2t,
                                              const float* b2, short* qkv, float* stats) {
  __shared__ short As[2 * 128 * 32];
  __shared__ short Bs[2 * 128 * 32];
  __shared__ float red[4][4];
  const int lane = threadIdx.x & 63, wv = threadIdx.x >> 6;
  const int wm = wv >> 1, wn = wv & 1;
  const int lg = lane >> 4, li = lane & 15;
  const int w = ((int)blockIdx.x & 7) * 192 + ((int)blockIdx.x >> 3);
  const int n0 = (w % 6) * 128;
  const int by = w / 6;
  const int b = by >> 5, ypair = by & 31;
  const short* xPb = xP + (long)b * 66 * 66 * 256;

  const int srow = wv * 16 + (lane >> 2);
  const int scol = (lane & 3) * 8;
  long baseA[2], baseB[2];
  #pragma unroll
  for (int j = 0; j < 2; ++j) {
    int r = j * 64 + srow;
    int yy = 2 * ypair + (r >> 6);
    int x = r & 63;
    baseA[j] = ((long)yy * 66 + x) * 256 + scol;
    baseB[j] = (long)(n0 + r) * 256 + scol;
  }
  short* ldsA = As + wv * 512;
  short* ldsB = Bs + wv * 512;
  const short* aRd = As + (wm * 64 + li) * 32 + lg * 8;
  const short* bRd = Bs + (wn * 64 + li) * 32 + lg * 8;

  fx4 acc[4][4] = {};
  for (int ks = 0; ks < 36; ++ks) {
    int tap = ks >> 2;
    int c0 = (ks & 3) * 64;
    int dy = tap / 3, dx = tap - dy * 3;
    long aoff = (long)(dy * 66 + dx) * 256 + c0;
    long boff = (long)tap * (768 * 256) + c0;
    gl_lds16(xPb + baseA[0] + aoff, ldsA);
    gl_lds16(xPb + baseA[1] + aoff, ldsA + 2048);
    gl_lds16(xPb + baseA[0] + aoff + 32, ldsA + 4096);
    gl_lds16(xPb + baseA[1] + aoff + 32, ldsA + 6144);
    gl_lds16(W2t + baseB[0] + boff, ldsB);
    gl_lds16(W2t + baseB[1] + boff, ldsB + 2048);
    gl_lds16(W2t + baseB[0] + boff + 32, ldsB + 4096);
    gl_lds16(W2t + baseB[1] + boff + 32, ldsB + 6144);
    __syncthreads();
    #pragma unroll
    for (int kk = 0; kk < 2; ++kk) {
      bfx8 af[4], bf[4];
      #pragma unroll
      for (int mi = 0; mi < 4; ++mi) af[mi] = *(const bfx8*)(aRd + kk * 4096 + mi * 16 * 32);
      #pragma unroll
      for (int ni = 0; ni < 4; ++ni) bf[ni] = *(const bfx8*)(bRd + kk * 4096 + ni * 16 * 32);
      #pragma unroll
      for (int mi = 0; mi < 4; ++mi)
        #pragma unroll
        for (int ni = 0; ni < 4; ++ni)
          MFMA16(acc[mi][ni], af[mi], bf[ni]);
    }
    __syncthreads();
  }

  const int g0 = n0 / 192;
  const int bnd = (g0 + 1) * 192;
  float sA = 0.0f, s2A = 0.0f, sB = 0.0f, s2B = 0.0f;
  const long prow0 = (long)b * 4096 + (long)ypair * 128 + wm * 64 + 4 * lg;
  #pragma unroll
  for (int ni = 0; ni < 4; ++ni) {
    int col = n0 + wn * 64 + ni * 16 + li;
    float bias = b2[col];
    bool inA = (col < bnd);
    #pragma unroll
    for (int mi = 0; mi < 4; ++mi) {
      long rb = prow0 + mi * 16;
      #pragma unroll
      for (int r = 0; r < 4; ++r) {
        float v = acc[mi][ni][r] + bias;
        if (inA) { sA += v; s2A += v * v; } else { sB += v; s2B += v * v; }
        qkv[(rb + r) * 768 + col] = f2bf(v);
      }
    }
  }
  #pragma unroll
  for (int off = 1; off < 64; off <<= 1) {
    sA += __shfl_xor(sA, off);  s2A += __shfl_xor(s2A, off);
    sB += __shfl_xor(sB, off);  s2B += __shfl_xor(s2B, off);
  }
  if (lane == 0) { red[wv][0] = sA; red[wv][1] = s2A; red[wv][2] = sB; red[wv][3] = s2B; }
  __syncthreads();
  if (threadIdx.x == 0) {
    float a1 = red[0][0] + red[1][0] + red[2][0] + red[3][0];
    float a2 = red[0][1] + red[1][1] + red[2][1] + red[3][1];
    atomicAdd(&stats[(b * 4 + g0) * 2], a1);
    atomicAdd(&stats[(b * 4 + g0) * 2 + 1], a2);
    if (bnd < n0 + 128) {
      float b1s = red[0][2] + red[1][2] + red[2][2] + red[3][2];
      float b2s = red[0][3] + red[1][3] + red[2][3] + red[3][3];
      atomicAdd(&stats[(b * 4 + g0 + 1) * 2], b1s);
      atomicAdd(&stats[(b * 4 + g0 + 1) * 2 + 1], b2s);
    }
  }
}

// fold GN affine into per-batch projection weights (stats finalized inline)
__global__ __launch_bounds__(256) void gn_fold(const float* stats, const float* gnw, const float* gnb,
                                               const float* inw, const float* inb,
                                               short* Wf, float* bfold) {
  const int lane = threadIdx.x & 63, wv = threadIdx.x >> 6;
  const int row = blockIdx.x * 4 + wv;
  const int b = row / 768, j = row - b * 768;
  const int cb = (j >> 8) << 8;
  const float nrm = 1.0f / (192.0f * 4096.0f);
  float part = 0.0f;
  #pragma unroll
  for (int i = 0; i < 4; ++i) {
    int c = lane + 64 * i;
    int cg = cb + c;
    int grp = cg / 192;
    float s1 = stats[(b * 4 + grp) * 2];
    float s2 = stats[(b * 4 + grp) * 2 + 1];
    float mu = s1 * nrm;
    float var = s2 * nrm - mu * mu;
    float rs = rsqrtf(var + 1e-5f);
    float s = rs * gnw[cg];
    float t = gnb[cg] - mu * s;
    float wv_ = inw[(long)j * 256 + c];
    Wf[(long)row * 256 + c] = f2bf(wv_ * s);
    part += t * wv_;
  }
  #pragma unroll
  for (int off = 1; off < 64; off <<= 1) part += __shfl_xor(part, off);
  if (lane == 0) bfold[row] = inb[j] + part;
}

// ---------------- local window attention (+ fused window mean -> oatm), XCD-swizzled ----------------
__global__ __launch_bounds__(256) void attn_local(const short* qk, const short* vhT,
                                                  short* oat, short* oatm) {
  __shared__ short Pl[4 * 64 * 72];
  const int lane = threadIdx.x & 63, h = threadIdx.x >> 6;
  const int lg = lane >> 4, li = lane & 15;
  // T1: XCD x handles batch x (64 consecutive windows) -> qk/vhT slices L2-resident
  const int bw = (((int)blockIdx.x & 7) << 6) | ((int)blockIdx.x >> 3);
  const int b = bw >> 6, wY = bw & 63;
  const long p0 = (long)bw * 64;

  bfx8 qf[4][2], kf[4][2];
  #pragma unroll
  for (int mi = 0; mi < 4; ++mi)
    #pragma unroll
    for (int ks = 0; ks < 2; ++ks) {
      qf[mi][ks] = *(const bfx8*)(qk + (p0 + 16 * mi + li) * 512 + h * 64 + 32 * ks + 8 * lg);
      kf[mi][ks] = *(const bfx8*)(qk + (p0 + 16 * mi + li) * 512 + 256 + h * 64 + 32 * ks + 8 * lg);
    }
  fx4 s[4][4] = {};
  #pragma unroll
  for (int mi = 0; mi < 4; ++mi)
    #pragma unroll
    for (int ni = 0; ni < 4; ++ni) {
      MFMA16(s[mi][ni], qf[mi][0], kf[ni][0]);
      MFMA16(s[mi][ni], qf[mi][1], kf[ni][1]);
    }
  #pragma unroll
  for (int mi = 0; mi < 4; ++mi)
    #pragma unroll
    for (int ni = 0; ni < 4; ++ni) s[mi][ni] *= 0.125f;

  #pragma unroll
  for (int mi = 0; mi < 4; ++mi)
    #pragma unroll
    for (int r = 0; r < 4; ++r) {
      float mx = fmaxf(fmaxf(s[mi][0][r], s[mi][1][r]), fmaxf(s[mi][2][r], s[mi][3][r]));
      for (int off = 1; off < 16; off <<= 1) mx = fmaxf(mx, __shfl_xor(mx, off));
      float e[4];
      float sum = 0.0f;
      #pragma unroll
      for (int ni = 0; ni < 4; ++ni) { e[ni] = expf(s[mi][ni][r] - mx); sum += e[ni]; }
      for (int off = 1; off < 16; off <<= 1) sum += __shfl_xor(sum, off);
      float inv = 1.0f / sum;
      int row = h * 64 + 16 * mi + 4 * lg + r;
      #pragma unroll
      for (int ni = 0; ni < 4; ++ni) Pl[row * 72 + 16 * ni + li] = f2bf(e[ni] * inv);
    }
  __syncthreads();

  fx4 o[4][4] = {};
  #pragma unroll
  for (int ks = 0; ks < 2; ++ks) {
    bfx8 pf[4], vf[4];
    #pragma unroll
    for (int mi = 0; mi < 4; ++mi)
      pf[mi] = *(const bfx8*)(&Pl[(h * 64 + 16 * mi + li) * 72 + 32 * ks + 8 * lg]);
    #pragma unroll
    for (int ni = 0; ni < 4; ++ni)
      vf[ni] = *(const bfx8*)(vhT + ((long)(b * 256 + h * 64 + 16 * ni + li)) * 4096 + wY * 64 + 32 * ks + 8 * lg);
    #pragma unroll
    for (int mi = 0; mi < 4; ++mi)
      #pragma unroll
      for (int ni = 0; ni < 4; ++ni) MFMA16(o[mi][ni], pf[mi], vf[ni]);
  }
  #pragma unroll
  for (int mi = 0; mi < 4; ++mi)
    #pragma unroll
    for (int ni = 0; ni < 4; ++ni)
      #pragma unroll
      for (int r = 0; r < 4; ++r)
        oat[(p0 + 16 * mi + 4 * lg + r) * 256 + h * 64 + 16 * ni + li] = f2bf(o[mi][ni][r]);

  #pragma unroll
  for (int ni = 0; ni < 4; ++ni) {
    float s2 = 0.0f;
    #pragma unroll
    for (int mi = 0; mi < 4; ++mi)
      #pragma unroll
      for (int r = 0; r < 4; ++r) s2 += o[mi][ni][r];
    s2 += __shfl_xor(s2, 16);
    s2 += __shfl_xor(s2, 32);
    if (lg == 0)
      oatm[(long)bw * 256 + h * 64 + 16 * ni + li] = f2bf(s2 * (1.0f / 64.0f));
  }
}

// ---------------- fused: per-batch global chain (redundant per block) + ep1 + ep2 + sigmoid ----------------
#define GP 272

DEV void mm_stage(const short* srcA, const short* Bw, long ldb, const float* biasN,
                  short* dstL, int wv, int lg, int li) {
  fx4 acc[4][4] = {};
  const short* aRd = srcA + li * GP + lg * 8;
  const short* bR = Bw + (long)(wv * 64 + li) * ldb + lg * 8;
  for (int kc = 0; kc < 256; kc += 32) {
    bfx8 af[4], bf[4];
    #pragma unroll
    for (int mi = 0; mi < 4; ++mi) af[mi] = *(const bfx8*)(aRd + mi * 16 * GP + kc);
    #pragma unroll
    for (int ni = 0; ni < 4; ++ni) bf[ni] = *(const bfx8*)(bR + (long)ni * 16 * ldb + kc);
    #pragma unroll
    for (int mi = 0; mi < 4; ++mi)
      #pragma unroll
      for (int ni = 0; ni < 4; ++ni) MFMA16(acc[mi][ni], af[mi], bf[ni]);
  }
  #pragma unroll
  for (int mi = 0; mi < 4; ++mi)
    #pragma unroll
    for (int ni = 0; ni < 4; ++ni) {
      int col = wv * 64 + ni * 16 + li;
      float bn = biasN[col];
      #pragma unroll
      for (int r = 0; r < 4; ++r) {
        int row = mi * 16 + 4 * lg + r;
        dstL[row * GP + col] = f2bf(acc[mi][ni][r] + bn);
      }
    }
}

union EpU {
  struct { short bufA[64 * GP]; short bufB[64 * GP]; float kh[4][256]; float vh[4][256]; } c;
  struct { short As[2 * 128 * 32]; short Bs[2 * 128 * 32]; short hl[128 * 140]; } m;
};

__global__ __launch_bounds__(256) void ep12(const short* oat, const short* oatm,
                                            const float* khv, const float* vhv,
                                            const short* Wo, const short* Wqkv, const short* Wep1,
                                            const short* Wcomb, const short* Wep2,
                                            const float* ob, const float* inb, const float* ebc,
                                            const float* e2b, float* out) {
  __shared__ EpU u;
  __shared__ float gcon_s[2][256];
  const int t = threadIdx.x;
  const int lane = t & 63, wv = t >> 6;
  const int wm = wv >> 1, wn = wv & 1;
  const int lg = lane >> 4, li = lane & 15;
  // T1: XCD x handles batch x (32 consecutive 128-row blocks)
  const int mb = (((int)blockIdx.x & 7) << 5) | ((int)blockIdx.x >> 3);
  const int m0 = mb * 128;
  const int b = m0 >> 12;           // batch
  const int ib = mb & 31;           // block-in-batch; windows ib*2, ib*2+1

  // ===== phase 1: per-batch global chain (redundant per block, fully parallel) =====
  {
    #pragma unroll
    for (int i = 0; i < 8; ++i) {
      int chunk = i * 256 + t;
      int row = chunk >> 5, colc = (chunk & 31) * 8;
      *(bfx8*)(u.c.bufA + row * GP + colc) =
          *(const bfx8*)(oatm + ((long)(b * 64 + row)) * 256 + colc);
    }
    #pragma unroll
    for (int key = 0; key < 4; ++key) {
      u.c.kh[key][t] = khv[(long)(b * 4 + key) * 256 + t];
      u.c.vh[key][t] = vhv[(long)(b * 4 + key) * 256 + t];
    }
  }
  __syncthreads();
  mm_stage(u.c.bufA, Wo, 256, ob, u.c.bufB, wv, lg, li);
  __syncthreads();
  mm_stage(u.c.bufB, Wqkv, 256, inb, u.c.bufA, wv, lg, li);
  __syncthreads();
  { // 4-key attention per (window p, head hh)
    int p = t >> 2, hh = t & 3;
    const short* qr = u.c.bufA + p * GP + hh * 64;
    float sc[4];
    #pragma unroll
    for (int key = 0; key < 4; ++key) {
      float s = 0.0f;
      for (int d = 0; d < 64; d += 8) {
        bfx8 q8 = *(const bfx8*)(qr + d);
        #pragma unroll
        for (int j = 0; j < 8; ++j) s += bf2f(q8[j]) * u.c.kh[key][hh * 64 + d + j];
      }
      sc[key] = s * 0.125f;
    }
    float mx = fmaxf(fmaxf(sc[0], sc[1]), fmaxf(sc[2], sc[3]));
    float e0 = expf(sc[0]-mx), e1 = expf(sc[1]-mx), e2 = expf(sc[2]-mx), e3 = expf(sc[3]-mx);
    float inv = 1.0f / (e0 + e1 + e2 + e3);
    e0 *= inv; e1 *= inv; e2 *= inv; e3 *= inv;
    short* orow = u.c.bufB + p * GP + hh * 64;
    for (int d = 0; d < 64; ++d) {
      float o = e0*u.c.vh[0][hh*64+d] + e1*u.c.vh[1][hh*64+d] +
                e2*u.c.vh[2][hh*64+d] + e3*u.c.vh[3][hh*64+d];
      orow[d] = f2bf(o);
    }
  }
  __syncthreads();
  mm_stage(u.c.bufB, Wo, 256, ob, u.c.bufA, wv, lg, li);
  __syncthreads();
  { // final: gcon rows for windows ib*2, ib*2+1 only -> gcon_s
    fx4 acc[4][4] = {};
    const short* aRd = u.c.bufA + li * GP + lg * 8;
    const short* bR = Wep1 + 256 + (long)(wv * 64 + li) * 512 + lg * 8;
    for (int kc = 0; kc < 256; kc += 32) {
      bfx8 af[4], bf[4];
      #pragma unroll
      for (int mi = 0; mi < 4; ++mi) af[mi] = *(const bfx8*)(aRd + mi * 16 * GP + kc);
      #pragma unroll
      for (int ni = 0; ni < 4; ++ni) bf[ni] = *(const bfx8*)(bR + (long)ni * 16 * 512 + kc);
      #pragma unroll
      for (int mi = 0; mi < 4; ++mi)
        #pragma unroll
        for (int ni = 0; ni < 4; ++ni) MFMA16(acc[mi][ni], af[mi], bf[ni]);
    }
    #pragma unroll
    for (int mi = 0; mi < 4; ++mi)
      #pragma unroll
      for (int ni = 0; ni < 4; ++ni) {
        int col = wv * 64 + ni * 16 + li;
        float bn = ebc[col];
        #pragma unroll
        for (int r = 0; r < 4; ++r) {
          int row = mi * 16 + 4 * lg + r;
          if ((row >> 1) == ib) gcon_s[row & 1][col] = acc[mi][ni][r] + bn;
        }
      }
  }
  __syncthreads();

  // ===== phase 2: ep1 (oat @ Wcomb^T + gcon) -> gelu -> hl; ep2 MFMA -> sigmoid -> out =====
  const int srow = wv * 16 + (lane >> 2);
  const int scol = (lane & 3) * 8;
  const short* pA0 = oat + (long)(m0 + srow) * 256 + scol;
  const short* pA1 = oat + (long)(m0 + 64 + srow) * 256 + scol;
  short* ldsA = u.m.As + wv * 512;
  short* ldsB = u.m.Bs + wv * 512;
  const short* aRd = u.m.As + (wm * 64 + li) * 32 + lg * 8;
  const short* bRd = u.m.Bs + (wn * 64 + li) * 32 + lg * 8;

  fx4 eacc[2] = {};
  for (int half = 0; half < 2; ++half) {
    const short* B = Wcomb + (long)(half * 128) * 256;
    const short* pB0 = B + (long)srow * 256 + scol;
    const short* pB1 = B + (long)(64 + srow) * 256 + scol;
    fx4 acc[4][4] = {};
    for (int kc = 0; kc < 256; kc += 64) {
      gl_lds16(pA0 + kc, ldsA);
      gl_lds16(pA1 + kc, ldsA + 2048);
      gl_lds16(pA0 + kc + 32, ldsA + 4096);
      gl_lds16(pA1 + kc + 32, ldsA + 6144);
      gl_lds16(pB0 + kc, ldsB);
      gl_lds16(pB1 + kc, ldsB + 2048);
      gl_lds16(pB0 + kc + 32, ldsB + 4096);
      gl_lds16(pB1 + kc + 32, ldsB + 6144);
      __syncthreads();
      #pragma unroll
      for (int kk = 0; kk < 2; ++kk) {
        bfx8 af[4], bf[4];
        #pragma unroll
        for (int mi = 0; mi < 4; ++mi) af[mi] = *(const bfx8*)(aRd + kk * 4096 + mi * 16 * 32);
        #pragma unroll
        for (int ni = 0; ni < 4; ++ni) bf[ni] = *(const bfx8*)(bRd + kk * 4096 + ni * 16 * 32);
        #pragma unroll
        for (int mi = 0; mi < 4; ++mi)
          #pragma unroll
          for (int ni = 0; ni < 4; ++ni)
            MFMA16(acc[mi][ni], af[mi], bf[ni]);
      }
      __syncthreads();
    }
    #pragma unroll
    for (int mi = 0; mi < 4; ++mi)
      #pragma unroll
      for (int ni = 0; ni < 4; ++ni) {
        int coll = wn * 64 + ni * 16 + li;
        int colg = half * 128 + coll;
        #pragma unroll
        for (int r = 0; r < 4; ++r) {
          int rowl = wm * 64 + mi * 16 + 4 * lg + r;
          float v = acc[mi][ni][r] + gcon_s[rowl >> 6][colg];
          u.m.hl[rowl * 140 + coll] = f2bf(gelu_f(v));
        }
      }
    __syncthreads();
    #pragma unroll
    for (int kc = 0; kc < 128; kc += 32) {
      bfx8 bf2v = *(const bfx8*)(Wep2 + (long)li * 256 + half * 128 + kc + lg * 8);
      #pragma unroll
      for (int mi = 0; mi < 2; ++mi) {
        bfx8 af = *(const bfx8*)(u.m.hl + (wv * 32 + mi * 16 + li) * 140 + kc + lg * 8);
        MFMA16(eacc[mi], af, bf2v);
      }
    }
    __syncthreads();
  }
  #pragma unroll
  for (int mi = 0; mi < 2; ++mi)
    #pragma unroll
    for (int r = 0; r < 4; ++r) {
      int row = m0 + wv * 32 + mi * 16 + 4 * lg + r;
      out[(long)row * 16 + li] = 1.0f / (1.0f + expf(-(eacc[mi][r] + e2b[li])));
    }
}

// ---------------- host ----------------
extern "C" void kernel_launch(void* const* d_in, const int* in_sizes, int n_in,
                              void* d_out, int out_size, void* d_ws, size_t ws_size,
                              hipStream_t stream) {
  (void)in_sizes; (void)n_in; (void)out_size; (void)ws_size;
  const float* fm  = (const float*)d_in[0];
  const float* txt = (const float*)d_in[1];
  const float* w1  = (const float*)d_in[2];
  const float* b1  = (const float*)d_in[3];
  const float* w2  = (const float*)d_in[4];
  const float* b2  = (const float*)d_in[5];
  const float* gnw = (const float*)d_in[6];
  const float* gnb = (const float*)d_in[7];
  const float* inw = (const float*)d_in[8];
  const float* inb = (const float*)d_in[9];
  const float* ow  = (const float*)d_in[10];
  const float* ob  = (const float*)d_in[11];
  const float* tw  = (const float*)d_in[12];
  const float* tb  = (const float*)d_in[13];
  const float* e1w = (const float*)d_in[14];
  const float* e1b = (const float*)d_in[15];
  const float* e2w = (const float*)d_in[16];
  const float* e2b = (const float*)d_in[17];
  float* out = (float*)d_out;

  char* base = (char*)d_ws;
  size_t off = 0;
  auto alloc = [&](size_t bytes) -> char* {
    char* r = base + off;
    off = (off + bytes + 255) & ~(size_t)255;
    return r;
  };
  short* W1bf = (short*)alloc(256 * 256 * 2);
  short* W2t  = (short*)alloc((size_t)9 * 768 * 256 * 2);
  short* Wqkv = (short*)alloc(768 * 256 * 2);
  short* Wo   = (short*)alloc(256 * 256 * 2);
  short* Wcomb= (short*)alloc(256 * 256 * 2);
  float* ebc  = (float*)alloc(256 * 4);
  short* Wtxt = (short*)alloc(256 * 512 * 2);
  short* Wep1 = (short*)alloc(256 * 512 * 2);
  short* Wep2 = (short*)alloc(16 * 256 * 2);
  short* xP   = (short*)alloc((size_t)8 * 66 * 66 * 256 * 2);
  short* qkv  = (short*)alloc((size_t)8 * 4096 * 768 * 2);
  float* stats= (float*)alloc(64 * 4);
  short* Wf   = (short*)alloc((size_t)8 * 768 * 256 * 2);
  float* bfold= (float*)alloc((size_t)8 * 768 * 4);
  short* qk   = (short*)alloc((size_t)32768 * 512 * 2);
  short* vhT  = (short*)alloc((size_t)8 * 4096 * 256 * 2);
  short* oat  = (short*)alloc((size_t)8 * 4096 * 256 * 2);
  short* oatm = (short*)alloc(512 * 256 * 2);
  float* khv  = (float*)alloc(8 * 4 * 256 * 4);
  float* vhv  = (float*)alloc(8 * 4 * 256 * 4);

  hipMemsetAsync(stats, 0, 64 * 4, stream);

  PrepArgs pa;
  pa.w1 = w1; pa.inw = inw; pa.ow = ow; pa.tw = tw; pa.e1w = e1w; pa.e2w = e2w;
  pa.txt = txt; pa.w2 = w2; pa.e1b = e1b; pa.ob = ob; pa.tb = tb; pa.inb = inb;
  pa.W1bf = W1bf; pa.Wqkv = Wqkv; pa.Wo = Wo; pa.Wtxt = Wtxt; pa.Wep1 = Wep1;
  pa.Wep2 = Wep2; pa.W2t = W2t; pa.Wcomb = Wcomb;
  pa.ebc = ebc; pa.khv = khv; pa.vhv = vhv;
  prep<<<1146, 256, 0, stream>>>(pa);

  tc1<<<512, 256, 0, stream>>>(fm, W1bf, b1, xP);

  conv2g<<<1536, 256, 0, stream>>>(xP, W2t, b2, qkv, stats);

  gn_fold<<<1536, 256, 0, stream>>>(stats, gnw, gnb, inw, inb, Wf, bfold);

  { // packed qk + v projections
    GemmP gq{};
    gq.A = qkv; gq.lda = 768; gq.sA = 4096L * 768;
    gq.B = Wf; gq.ldb = 256; gq.sB = 768L * 256;
    gq.O = qk; gq.ldo = 512; gq.sO = 4096L * 512;
    gq.biasN = bfold; gq.sBN = 768;
    gq.aShift = 256;
    gq.M = 4096; gq.N = 512; gq.K = 256;
    GemmP gv{};
    gv.A = Wf + 512 * 256; gv.lda = 256; gv.sA = 768L * 256;
    gv.B = qkv + 512; gv.ldb = 768; gv.sB = 4096L * 768;
    gv.O = vhT; gv.ldo = 4096; gv.sO = 256L * 4096;
    gv.biasM = bfold + 512; gv.sBM = 768;
    gv.M = 256; gv.N = 4096; gv.K = 256;
    projk<<<1536, 256, 0, stream>>>(gq, gv);
  }

  attn_local<<<512, 256, 0, stream>>>(qk, vhT, oat, oatm);

  ep12<<<256, 256, 0, stream>>>(oat, oatm, khv, vhv, Wo, Wqkv, Wep1, Wcomb, Wep2,
                                ob, inb, ebc, e2b, out);
}